// Round 6
// baseline (949.305 us; speedup 1.0000x reference)
//
#include <hip/hip_runtime.h>
#include <stdint.h>

typedef __attribute__((ext_vector_type(8))) __bf16 bf16x8;
typedef __attribute__((ext_vector_type(4))) float f32x4;

template <int V> struct IC { static constexpr int value = V; };

__device__ __forceinline__ unsigned short f2bf(float f) {
  unsigned u = __float_as_uint(f);
  u += 0x7FFFu + ((u >> 16) & 1u);
  return (unsigned short)(u >> 16);
}
__device__ __forceinline__ float bf2f(unsigned short u) {
  return __uint_as_float((unsigned)u << 16);
}

__device__ __forceinline__ void gload16(const void* g, void* lds) {
  __builtin_amdgcn_global_load_lds((const __attribute__((address_space(1))) void*)g,
                                   (__attribute__((address_space(3))) void*)lds, 16, 0, 0);
}

// ---------------- prep kernels ----------------

// one block per row: f32 row -> bf16 row (stride ldy) + rs[row] = 1/sqrt(sumsq+eps)
__global__ __launch_bounds__(256) void conv_norm_row(const float* __restrict__ x,
                                                     unsigned short* __restrict__ y,
                                                     float* __restrict__ rs,
                                                     int cols, int ldy) {
  const int row = blockIdx.x;
  const float4* x4 = (const float4*)(x + (size_t)row * cols);
  ushort4* y4 = (ushort4*)(y + (size_t)row * ldy);
  const int n4 = cols >> 2;
  float s = 0.f;
  for (int i = threadIdx.x; i < n4; i += 256) {
    float4 t = x4[i];
    s += t.x * t.x + t.y * t.y + t.z * t.z + t.w * t.w;
    ushort4 o;
    o.x = f2bf(t.x); o.y = f2bf(t.y); o.z = f2bf(t.z); o.w = f2bf(t.w);
    y4[i] = o;
  }
#pragma unroll
  for (int o = 32; o >= 1; o >>= 1) s += __shfl_xor(s, o, 64);
  __shared__ float red[4];
  if ((threadIdx.x & 63) == 0) red[threadIdx.x >> 6] = s;
  __syncthreads();
  if (threadIdx.x == 0) {
    const float tot = red[0] + red[1] + red[2] + red[3];
    rs[row] = 1.0f / sqrtf(tot + 1e-6f);
  }
}

// two f32->bf16 converts in one launch (n in float4 units)
__global__ __launch_bounds__(256) void convert2_bf16(const float* __restrict__ x1,
                                                     unsigned short* __restrict__ y1, long n1,
                                                     const float* __restrict__ x2,
                                                     unsigned short* __restrict__ y2, long n2) {
  long i = (long)blockIdx.x * 256 + threadIdx.x;
  const long stride = (long)gridDim.x * 256;
  const long tot = n1 + n2;
  for (; i < tot; i += stride) {
    const float4* src; ushort4* dst; long j;
    if (i < n1) { src = (const float4*)x1; dst = (ushort4*)y1; j = i; }
    else        { src = (const float4*)x2; dst = (ushort4*)y2; j = i - n1; }
    float4 t = src[j];
    ushort4 o;
    o.x = f2bf(t.x); o.y = f2bf(t.y); o.z = f2bf(t.z); o.w = f2bf(t.w);
    dst[j] = o;
  }
}

// x [R][C] f32 -> y [C][R] bf16
__global__ __launch_bounds__(256) void transpose_bf16(const float* __restrict__ x,
                                                      unsigned short* __restrict__ y,
                                                      int R, int C) {
  __shared__ float tile[64][65];
  const int r0 = blockIdx.y * 64;
  const int c0 = blockIdx.x * 64;
#pragma unroll
  for (int i = 0; i < 16; ++i) {
    int lin = i * 256 + threadIdx.x;
    int r = lin >> 6, c = lin & 63;
    tile[r][c] = x[(size_t)(r0 + r) * C + c0 + c];
  }
  __syncthreads();
#pragma unroll
  for (int i = 0; i < 16; ++i) {
    int lin = i * 256 + threadIdx.x;
    int tr = lin >> 6, tc = lin & 63;
    y[(size_t)(c0 + tr) * R + r0 + tc] = f2bf(tile[tc][tr]);
  }
}

// ---------------- sparsemax (scaled raw sims -> dense bf16 weights) ----------------
__global__ __launch_bounds__(256) void sparsemax_scaled(
    const unsigned short* __restrict__ simb, const float* __restrict__ rs,
    const float* __restrict__ cs, unsigned short* __restrict__ w, int Mc) {
  const int row = blockIdx.x;
  const int tid = threadIdx.x;
  const float r = rs[row];
  const ushort4* z4 = (const ushort4*)(simb + (size_t)row * Mc);
  const float4* c4 = (const float4*)cs;
  float z[32];
#pragma unroll
  for (int i = 0; i < 8; ++i) {
    ushort4 v = z4[i * 256 + tid];
    float4 c = c4[i * 256 + tid];
    z[i * 4 + 0] = bf2f(v.x) * r * c.x;
    z[i * 4 + 1] = bf2f(v.y) * r * c.y;
    z[i * 4 + 2] = bf2f(v.z) * r * c.z;
    z[i * 4 + 3] = bf2f(v.w) * r * c.w;
  }
  float mx = z[0];
#pragma unroll
  for (int j = 1; j < 32; ++j) mx = fmaxf(mx, z[j]);
#pragma unroll
  for (int o = 32; o >= 1; o >>= 1) mx = fmaxf(mx, __shfl_xor(mx, o, 64));
  __shared__ float red[4];
  const int wv = tid >> 6, ln = tid & 63;
  if (ln == 0) red[wv] = mx;
  __syncthreads();
  mx = fmaxf(fmaxf(red[0], red[1]), fmaxf(red[2], red[3]));

  float lo = mx - 1.0f, hi = mx;
  for (int it = 0; it < 22; ++it) {   // 2^-22 tau resolution << bf16 weight quantum
    const float tau = 0.5f * (lo + hi);
    float s = 0.f;
#pragma unroll
    for (int j = 0; j < 32; ++j) s += fmaxf(z[j] - tau, 0.f);
#pragma unroll
    for (int o = 32; o >= 1; o >>= 1) s += __shfl_xor(s, o, 64);
    __syncthreads();
    if (ln == 0) red[wv] = s;
    __syncthreads();
    s = red[0] + red[1] + red[2] + red[3];
    if (s > 1.0f) lo = tau; else hi = tau;
  }
  const float tau = 0.5f * (lo + hi);
  unsigned short* wrow = w + (size_t)row * Mc;
#pragma unroll
  for (int i = 0; i < 8; ++i) {
    ushort4 o;
    o.x = f2bf(fmaxf(z[i * 4 + 0] - tau, 0.f));
    o.y = f2bf(fmaxf(z[i * 4 + 1] - tau, 0.f));
    o.z = f2bf(fmaxf(z[i * 4 + 2] - tau, 0.f));
    o.w = f2bf(fmaxf(z[i * 4 + 3] - tau, 0.f));
    ((ushort4*)wrow)[i * 256 + tid] = o;
  }
}

// fc2 split-K reduce: out[r][c<1000] = p0 + p1 + bias
__global__ __launch_bounds__(256) void fc2_reduce(const float* __restrict__ p0,
                                                  const float* __restrict__ p1,
                                                  const float* __restrict__ bias,
                                                  float* __restrict__ out) {
  const int r = blockIdx.x, t = threadIdx.x;
  if (t < 250) {
    float4 a = ((const float4*)(p0 + (size_t)r * 1024))[t];
    float4 b = ((const float4*)(p1 + (size_t)r * 1024))[t];
    float4 c = ((const float4*)bias)[t];
    float4 o;
    o.x = a.x + b.x + c.x; o.y = a.y + b.y + c.y;
    o.z = a.z + b.z + c.z; o.w = a.w + b.w + c.w;
    ((float4*)(out + (size_t)r * 1000))[t] = o;
  }
}

// ---------------- GEMM 128x128 (m97 structure) ----------------
// EPI 3: plain bf16 (ldc). EPI 4: f32 partial (ldc), no bias.
template <int EPI>
__global__ __launch_bounds__(256, 2) void gemm_bt(
    const unsigned short* __restrict__ A, const unsigned short* __restrict__ Bt,
    float* __restrict__ Cf, unsigned short* __restrict__ Cb,
    int M, int N, int K, int lda, int ldb, int ldc) {
  __shared__ __align__(16) unsigned short Al[128 * 32];
  __shared__ __align__(16) unsigned short Bl[128 * 32];

  const int tid = threadIdx.x;
  const int wave = tid >> 6;
  const int lane = tid & 63;
  const int bm = blockIdx.y * 128;
  const int bn = blockIdx.x * 128;
  const int wr = (wave >> 1) * 64;
  const int wc = (wave & 1) * 64;

  f32x4 acc[4][4] = {};

  const int srow = tid >> 2;
  const int scol = (tid & 3) * 8;
  const unsigned short* Ag = A + (size_t)(bm + srow) * lda + scol;
  const unsigned short* Bg = Bt + (size_t)(bn + srow) * ldb + scol;
  char* Alb = (char*)Al + wave * 1024;
  char* Blb = (char*)Bl + wave * 1024;

  const int fr = lane & 15;
  const int kq = lane >> 4;
  const unsigned short* Ard = Al + (wr + fr) * 32 + kq * 8;
  const unsigned short* Brd = Bl + (wc + fr) * 32 + kq * 8;

  for (int kt = 0; kt < K; kt += 32) {
    gload16(Ag + kt, Alb);
    gload16(Ag + kt + (size_t)64 * lda, Alb + 4096);
    gload16(Bg + kt, Blb);
    gload16(Bg + kt + (size_t)64 * ldb, Blb + 4096);
    __syncthreads();
    bf16x8 af[4], bfr[4];
#pragma unroll
    for (int m = 0; m < 4; ++m) af[m] = *(const bf16x8*)(Ard + m * 16 * 32);
#pragma unroll
    for (int n = 0; n < 4; ++n) bfr[n] = *(const bf16x8*)(Brd + n * 16 * 32);
#pragma unroll
    for (int m = 0; m < 4; ++m)
#pragma unroll
      for (int n = 0; n < 4; ++n)
        acc[m][n] = __builtin_amdgcn_mfma_f32_16x16x32_bf16(af[m], bfr[n], acc[m][n], 0, 0, 0);
    __syncthreads();
  }

  const int fq = lane >> 4;
#pragma unroll
  for (int m = 0; m < 4; ++m) {
    const int row0 = bm + wr + m * 16 + fq * 4;
#pragma unroll
    for (int n = 0; n < 4; ++n) {
      const int col = bn + wc + n * 16 + fr;
#pragma unroll
      for (int r = 0; r < 4; ++r) {
        float v = acc[m][n][r];
        if constexpr (EPI == 3) {
          Cb[(size_t)(row0 + r) * ldc + col] = f2bf(v);
        } else {
          Cf[(size_t)(row0 + r) * ldc + col] = v;
        }
      }
    }
  }
}

// ---------------- GEMM 256x256, BK=64, 8-wave, 4-phase, compile-time dbuf ----------
// Round-2 skeleton (same barriers/stage slots/counted vmcnt), but:
//  - K-loop unrolled x2 so the double-buffer index is COMPILE-TIME (no per-access
//    buf arithmetic; ds offsets fold to base+imm; staging bases precomputed).
//  - no blanket lgkmcnt(0)/sched_barrier around MFMA: operand waits come from
//    dataflow (compiler partial lgkmcnt), sched_barrier(0) only after phase-end
//    barriers (blocks read hoisting above the barrier) and after vmcnt asm.
// EPI 1: +bias relu bf16. EPI 2: plain bf16.
template <int EPI>
__global__ __launch_bounds__(512, 1) void gemm256(
    const unsigned short* __restrict__ A, const unsigned short* __restrict__ Bt,
    const float* __restrict__ bias, unsigned short* __restrict__ Cb,
    int M, int N, int K, int lda, int ldc) {
  __shared__ __align__(16) unsigned short lds[2][2][256 * 64];  // 128 KiB

  const int tid = threadIdx.x;
  const int wid = tid >> 6;
  const int lane = tid & 63;
  const int wr = wid >> 2;      // 0..1  (128-row band)
  const int wc = wid & 3;       // 0..3  (64-col band)
  const int fr = lane & 15;
  const int kq = lane >> 4;

  // bijective XCD swizzle (m204)
  const int nx = gridDim.x;
  const int nwg = nx * gridDim.y;
  const int bid = blockIdx.y * nx + blockIdx.x;
  const int q = nwg >> 3, r8 = nwg & 7;
  const int xcd = bid & 7, idx = bid >> 3;
  const int wg = (xcd < r8 ? xcd * (q + 1) : r8 * (q + 1) + (xcd - r8) * q) + idx;
  const int bn = (wg % nx) * 256;
  const int bm = (wg / nx) * 256;

  const int NT = K >> 6;   // assumed even (K multiple of 128)

  // staging: precomputed per-lane global bases [mat][half][iss]
  const int st_r = tid >> 3;
  const int st_x = (tid & 7) << 4;
  const int colb = st_x ^ ((st_r & 7) << 4);
  const unsigned short* gbase[2][2][2];
#pragma unroll
  for (int mat = 0; mat < 2; ++mat)
#pragma unroll
    for (int half = 0; half < 2; ++half)
#pragma unroll
      for (int iss = 0; iss < 2; ++iss) {
        const int row = half * 128 + iss * 64 + st_r;
        gbase[mat][half][iss] =
            (mat ? Bt + (size_t)(bn + row) * K : A + (size_t)(bm + row) * lda) + (colb >> 1);
      }
  const int widb = wid << 10;

  auto stage = [&](auto dbufc, int mat, int half, int kt) {
    constexpr int dbuf = decltype(dbufc)::value;
#pragma unroll
    for (int iss = 0; iss < 2; ++iss) {
      const unsigned short* g = gbase[mat][half][iss] + ((size_t)kt << 6);
      char* l = (char*)&lds[dbuf][mat][0] + (half * 2 + iss) * 8192 + widb;
      gload16(g, l);
    }
  };

  const int swz = (fr & 7) << 4;
  const int arow = (wr * 128 + fr) * 128;   // byte base of this lane's A rows
  const int brow = (wc * 64 + fr) * 128;    // byte base of this lane's B rows
  const int col0 = (kq * 16) ^ swz;
  const int col1 = (64 + kq * 16) ^ swz;
  auto rdA = [&](auto bufc, int mh, int m, int kk) -> bf16x8 {
    constexpr int buf = decltype(bufc)::value;
    const int off = arow + mh * 8192 + m * 2048 + (kk ? col1 : col0);
    return *(const bf16x8*)((const char*)&lds[buf][0][0] + off);
  };
  auto rdB = [&](auto bufc, int nh, int n, int kk) -> bf16x8 {
    constexpr int buf = decltype(bufc)::value;
    const int off = brow + nh * 4096 + n * 2048 + (kk ? col1 : col0);
    return *(const bf16x8*)((const char*)&lds[buf][1][0] + off);
  };

  f32x4 acc[8][4] = {};
  bf16x8 a[4][2], b0[2][2], b1[2][2];

  // ---- prologue: K-tile 0 (all 4 halves) + K-tile 1 (B0, A0)
  stage(IC<0>{}, 1, 0, 0);
  stage(IC<0>{}, 0, 0, 0);
  stage(IC<0>{}, 1, 1, 0);
  stage(IC<0>{}, 0, 1, 0);
  if (NT > 1) {
    stage(IC<1>{}, 1, 0, 1);
    stage(IC<1>{}, 0, 0, 1);
    asm volatile("s_waitcnt vmcnt(4)" ::: "memory");
  } else {
    asm volatile("s_waitcnt vmcnt(0)" ::: "memory");
  }
  __builtin_amdgcn_sched_barrier(0);
  __builtin_amdgcn_s_barrier();
  __builtin_amdgcn_sched_barrier(0);

  auto ktile = [&](auto bufc, int kt) {
    constexpr int buf = decltype(bufc)::value;
    constexpr int nbuf = buf ^ 1;
    IC<buf> B_; IC<nbuf> NB_;

    // ===== ph0: read A0+B0(buf); stage B1(kt+1); MFMA quad(0,0)
#pragma unroll
    for (int m = 0; m < 4; ++m) {
      a[m][0] = rdA(B_, 0, m, 0);
      a[m][1] = rdA(B_, 0, m, 1);
    }
#pragma unroll
    for (int n = 0; n < 2; ++n) {
      b0[n][0] = rdB(B_, 0, n, 0);
      b0[n][1] = rdB(B_, 0, n, 1);
    }
    if (kt + 1 < NT) stage(NB_, 1, 1, kt + 1);
    __builtin_amdgcn_s_barrier();
    __builtin_amdgcn_s_setprio(1);
#pragma unroll
    for (int m = 0; m < 4; ++m)
#pragma unroll
      for (int n = 0; n < 2; ++n)
#pragma unroll
        for (int kk = 0; kk < 2; ++kk)
          acc[m][n] = __builtin_amdgcn_mfma_f32_16x16x32_bf16(a[m][kk], b0[n][kk], acc[m][n], 0, 0, 0);
    __builtin_amdgcn_s_setprio(0);
    __builtin_amdgcn_s_barrier();
    __builtin_amdgcn_sched_barrier(0);

    // ===== ph1: read B1(buf); stage A1(kt+1); MFMA quad(0,1)
#pragma unroll
    for (int n = 0; n < 2; ++n) {
      b1[n][0] = rdB(B_, 1, n, 0);
      b1[n][1] = rdB(B_, 1, n, 1);
    }
    if (kt + 1 < NT) stage(NB_, 0, 1, kt + 1);
    __builtin_amdgcn_s_barrier();
    __builtin_amdgcn_s_setprio(1);
#pragma unroll
    for (int m = 0; m < 4; ++m)
#pragma unroll
      for (int n = 0; n < 2; ++n)
#pragma unroll
        for (int kk = 0; kk < 2; ++kk)
          acc[m][n + 2] = __builtin_amdgcn_mfma_f32_16x16x32_bf16(a[m][kk], b1[n][kk], acc[m][n + 2], 0, 0, 0);
    __builtin_amdgcn_s_setprio(0);
    __builtin_amdgcn_s_barrier();
    __builtin_amdgcn_sched_barrier(0);

    // ===== ph2: read A1(buf); stage B0(kt+2 -> buf); MFMA quad(1,1)
#pragma unroll
    for (int m = 0; m < 4; ++m) {
      a[m][0] = rdA(B_, 1, m, 0);
      a[m][1] = rdA(B_, 1, m, 1);
    }
    if (kt + 2 < NT) stage(B_, 1, 0, kt + 2);
    __builtin_amdgcn_s_barrier();
    __builtin_amdgcn_s_setprio(1);
#pragma unroll
    for (int m = 0; m < 4; ++m)
#pragma unroll
      for (int n = 0; n < 2; ++n)
#pragma unroll
        for (int kk = 0; kk < 2; ++kk)
          acc[m + 4][n + 2] = __builtin_amdgcn_mfma_f32_16x16x32_bf16(a[m][kk], b1[n][kk], acc[m + 4][n + 2], 0, 0, 0);
    __builtin_amdgcn_s_setprio(0);
    __builtin_amdgcn_s_barrier();
    __builtin_amdgcn_sched_barrier(0);

    // ===== ph3: stage A0(kt+2 -> buf); counted vmcnt; MFMA quad(1,0)
    if (kt + 2 < NT) {
      stage(B_, 0, 0, kt + 2);
      asm volatile("s_waitcnt vmcnt(4)" ::: "memory");
    } else {
      asm volatile("s_waitcnt vmcnt(0)" ::: "memory");
    }
    __builtin_amdgcn_sched_barrier(0);
    __builtin_amdgcn_s_barrier();
    __builtin_amdgcn_s_setprio(1);
#pragma unroll
    for (int m = 0; m < 4; ++m)
#pragma unroll
      for (int n = 0; n < 2; ++n)
#pragma unroll
        for (int kk = 0; kk < 2; ++kk)
          acc[m + 4][n] = __builtin_amdgcn_mfma_f32_16x16x32_bf16(a[m][kk], b0[n][kk], acc[m + 4][n], 0, 0, 0);
    __builtin_amdgcn_s_setprio(0);
    __builtin_amdgcn_s_barrier();
    __builtin_amdgcn_sched_barrier(0);
  };

  for (int kt = 0; kt < NT; kt += 2) {
    ktile(IC<0>{}, kt);
    ktile(IC<1>{}, kt + 1);
  }

  // ---- epilogue
  const int fq = lane >> 4;
#pragma unroll
  for (int m = 0; m < 8; ++m) {
    const int row0 = bm + wr * 128 + m * 16 + fq * 4;
#pragma unroll
    for (int n = 0; n < 4; ++n) {
      const int col = bn + wc * 64 + n * 16 + fr;
#pragma unroll
      for (int r = 0; r < 4; ++r) {
        float v = acc[m][n][r];
        if constexpr (EPI == 1) {
          v = fmaxf(v + bias[col], 0.0f);
          Cb[(size_t)(row0 + r) * ldc + col] = f2bf(v);
        } else {
          Cb[(size_t)(row0 + r) * ldc + col] = f2bf(v);
        }
      }
    }
  }
}

// ---------------- launch ----------------
extern "C" void kernel_launch(void* const* d_in, const int* in_sizes, int n_in,
                              void* d_out, int out_size, void* d_ws, size_t ws_size,
                              hipStream_t stream) {
  const float* enc  = (const float*)d_in[0];
  const float* mem  = (const float*)d_in[1];
  const float* fw1  = (const float*)d_in[2];
  const float* fb1  = (const float*)d_in[3];
  const float* fw2  = (const float*)d_in[4];
  const float* fb2  = (const float*)d_in[5];
  float* out = (float*)d_out;

  const int B = 4096, M = 8192, D = 2048, HID = 8192, OUT = 1000, OUTP = 1024;

  char* p = (char*)d_ws;
  auto alloc = [&](size_t bytes) {
    char* r = p;
    p += (bytes + 255) & ~(size_t)255;
    return r;
  };
  unsigned short* memB = (unsigned short*)alloc((size_t)M * D * 2);        // 32 MB raw bf16
  unsigned short* memT = (unsigned short*)alloc((size_t)D * M * 2);        // 32 MB raw^T
  unsigned short* w1   = (unsigned short*)alloc((size_t)HID * 2 * D * 2);  // 64 MB
  unsigned short* w2   = (unsigned short*)alloc((size_t)OUTP * HID * 2);   // 16 MB
  unsigned short* wts  = (unsigned short*)alloc((size_t)B * M * 2);        // 64 MB
  unsigned short* fin  = (unsigned short*)alloc((size_t)B * 2 * D * 2);    // 32 MB
  float* rs            = (float*)alloc((size_t)B * 4);
  float* cs            = (float*)alloc((size_t)M * 4);
  float* p0            = (float*)alloc((size_t)B * OUTP * 4);              // 16 MB
  float* p1            = (float*)alloc((size_t)B * OUTP * 4);              // 16 MB
  unsigned short* hid  = (unsigned short*)alloc((size_t)B * HID * 2);      // 64 MB
  unsigned short* simb = hid;  // alias: simb dead before fc1 writes hid

  // prep
  conv_norm_row<<<B, 256, 0, stream>>>(enc, fin, rs, D, 2 * D);
  conv_norm_row<<<M, 256, 0, stream>>>(mem, memB, cs, D, D);
  transpose_bf16<<<dim3(D / 64, M / 64), 256, 0, stream>>>(mem, memT, M, D);
  convert2_bf16<<<2048, 256, 0, stream>>>(fw1, w1, (long)HID * 2 * D / 4,
                                          fw2, w2, (long)OUT * HID / 4);

  // raw sims = bf16(enc) @ bf16(mem)^T  [B, M] -> bf16 (norms folded into sparsemax)
  gemm256<2><<<dim3(M / 256, B / 256), 512, 0, stream>>>(fin, memB, nullptr, simb,
                                                         B, M, D, 2 * D, M);
  // sparsemax(z * rs * cs) -> dense bf16 weights
  sparsemax_scaled<<<B, 256, 0, stream>>>(simb, rs, cs, wts, M);
  // fin[:, D:2D) = wts @ mem  (dense, fused bf16 store)
  gemm_bt<3><<<dim3(D / 128, B / 128), 256, 0, stream>>>(wts, memT, nullptr, fin + D,
                                                         B, D, M, M, M, 2 * D);
  // hidden = relu(fin @ fc1_w^T + b1) -> bf16
  gemm256<1><<<dim3(HID / 256, B / 256), 512, 0, stream>>>(fin, w1, fb1, hid,
                                                           B, HID, 2 * D, 2 * D, HID);
  // out = hidden @ fc2_w^T + b2 : split-K=2 partials + reduce
  gemm_bt<4><<<dim3(OUTP / 128, B / 128), 256, 0, stream>>>(hid, w2, p0, nullptr,
                                                            B, OUTP, HID / 2, HID, HID, OUTP);
  gemm_bt<4><<<dim3(OUTP / 128, B / 128), 256, 0, stream>>>(hid + HID / 2, w2 + HID / 2, p1, nullptr,
                                                            B, OUTP, HID / 2, HID, HID, OUTP);
  fc2_reduce<<<B, 256, 0, stream>>>(p0, p1, fb2, out);
}

// Round 8
// 871.569 us; speedup vs baseline: 1.0892x; 1.0892x over previous
//
#include <hip/hip_runtime.h>
#include <stdint.h>

typedef __attribute__((ext_vector_type(8))) __bf16 bf16x8;
typedef __attribute__((ext_vector_type(4))) float f32x4;

template <int V> struct IC { static constexpr int value = V; };

__device__ __forceinline__ unsigned short f2bf(float f) {
  unsigned u = __float_as_uint(f);
  u += 0x7FFFu + ((u >> 16) & 1u);
  return (unsigned short)(u >> 16);
}
__device__ __forceinline__ float bf2f(unsigned short u) {
  return __uint_as_float((unsigned)u << 16);
}

__device__ __forceinline__ void gload16(const void* g, void* lds) {
  __builtin_amdgcn_global_load_lds((const __attribute__((address_space(1))) void*)g,
                                   (__attribute__((address_space(3))) void*)lds, 16, 0, 0);
}

// ---------------- prep kernels ----------------

// one block per row: f32 row -> bf16 row (stride ldy) + rs[row] = 1/sqrt(sumsq+eps)
__global__ __launch_bounds__(256) void conv_norm_row(const float* __restrict__ x,
                                                     unsigned short* __restrict__ y,
                                                     float* __restrict__ rs,
                                                     int cols, int ldy) {
  const int row = blockIdx.x;
  const float4* x4 = (const float4*)(x + (size_t)row * cols);
  ushort4* y4 = (ushort4*)(y + (size_t)row * ldy);
  const int n4 = cols >> 2;
  float s = 0.f;
  for (int i = threadIdx.x; i < n4; i += 256) {
    float4 t = x4[i];
    s += t.x * t.x + t.y * t.y + t.z * t.z + t.w * t.w;
    ushort4 o;
    o.x = f2bf(t.x); o.y = f2bf(t.y); o.z = f2bf(t.z); o.w = f2bf(t.w);
    y4[i] = o;
  }
#pragma unroll
  for (int o = 32; o >= 1; o >>= 1) s += __shfl_xor(s, o, 64);
  __shared__ float red[4];
  if ((threadIdx.x & 63) == 0) red[threadIdx.x >> 6] = s;
  __syncthreads();
  if (threadIdx.x == 0) {
    const float tot = red[0] + red[1] + red[2] + red[3];
    rs[row] = 1.0f / sqrtf(tot + 1e-6f);
  }
}

// two f32->bf16 converts in one launch (n in float4 units)
__global__ __launch_bounds__(256) void convert2_bf16(const float* __restrict__ x1,
                                                     unsigned short* __restrict__ y1, long n1,
                                                     const float* __restrict__ x2,
                                                     unsigned short* __restrict__ y2, long n2) {
  long i = (long)blockIdx.x * 256 + threadIdx.x;
  const long stride = (long)gridDim.x * 256;
  const long tot = n1 + n2;
  for (; i < tot; i += stride) {
    const float4* src; ushort4* dst; long j;
    if (i < n1) { src = (const float4*)x1; dst = (ushort4*)y1; j = i; }
    else        { src = (const float4*)x2; dst = (ushort4*)y2; j = i - n1; }
    float4 t = src[j];
    ushort4 o;
    o.x = f2bf(t.x); o.y = f2bf(t.y); o.z = f2bf(t.z); o.w = f2bf(t.w);
    dst[j] = o;
  }
}

// bf16 [R][C] -> bf16 [C][R], 64x64 tiles, ushort4 both sides
__global__ __launch_bounds__(256) void transpose_bb(const unsigned short* __restrict__ x,
                                                    unsigned short* __restrict__ y,
                                                    int R, int C) {
  __shared__ unsigned short tile[64][65];
  const int r0 = blockIdx.y * 64;
  const int c0 = blockIdx.x * 64;
#pragma unroll
  for (int i = 0; i < 4; ++i) {
    int lin = i * 256 + threadIdx.x;
    int r = lin >> 4, c4 = (lin & 15) * 4;
    ushort4 v = *(const ushort4*)(x + (size_t)(r0 + r) * C + c0 + c4);
    tile[r][c4 + 0] = v.x; tile[r][c4 + 1] = v.y;
    tile[r][c4 + 2] = v.z; tile[r][c4 + 3] = v.w;
  }
  __syncthreads();
#pragma unroll
  for (int i = 0; i < 4; ++i) {
    int lin = i * 256 + threadIdx.x;
    int c = lin >> 4, r4 = (lin & 15) * 4;
    ushort4 o;
    o.x = tile[r4 + 0][c]; o.y = tile[r4 + 1][c];
    o.z = tile[r4 + 2][c]; o.w = tile[r4 + 3][c];
    *(ushort4*)(y + (size_t)(c0 + c) * R + r0 + r4) = o;
  }
}

// ---------------- sparsemax (scaled raw sims -> dense bf16 weights) ----------------
__global__ __launch_bounds__(256) void sparsemax_scaled(
    const unsigned short* __restrict__ simb, const float* __restrict__ rs,
    const float* __restrict__ cs, unsigned short* __restrict__ w, int Mc) {
  const int row = blockIdx.x;
  const int tid = threadIdx.x;
  const float r = rs[row];
  const ushort4* z4 = (const ushort4*)(simb + (size_t)row * Mc);
  const float4* c4 = (const float4*)cs;
  float z[32];
#pragma unroll
  for (int i = 0; i < 8; ++i) {
    ushort4 v = z4[i * 256 + tid];
    float4 c = c4[i * 256 + tid];
    z[i * 4 + 0] = bf2f(v.x) * r * c.x;
    z[i * 4 + 1] = bf2f(v.y) * r * c.y;
    z[i * 4 + 2] = bf2f(v.z) * r * c.z;
    z[i * 4 + 3] = bf2f(v.w) * r * c.w;
  }
  float mx = z[0];
#pragma unroll
  for (int j = 1; j < 32; ++j) mx = fmaxf(mx, z[j]);
#pragma unroll
  for (int o = 32; o >= 1; o >>= 1) mx = fmaxf(mx, __shfl_xor(mx, o, 64));
  __shared__ float red[4];
  const int wv = tid >> 6, ln = tid & 63;
  if (ln == 0) red[wv] = mx;
  __syncthreads();
  mx = fmaxf(fmaxf(red[0], red[1]), fmaxf(red[2], red[3]));

  float lo = mx - 1.0f, hi = mx;
  for (int it = 0; it < 22; ++it) {
    const float tau = 0.5f * (lo + hi);
    float s = 0.f;
#pragma unroll
    for (int j = 0; j < 32; ++j) s += fmaxf(z[j] - tau, 0.f);
#pragma unroll
    for (int o = 32; o >= 1; o >>= 1) s += __shfl_xor(s, o, 64);
    __syncthreads();
    if (ln == 0) red[wv] = s;
    __syncthreads();
    s = red[0] + red[1] + red[2] + red[3];
    if (s > 1.0f) lo = tau; else hi = tau;
  }
  const float tau = 0.5f * (lo + hi);
  unsigned short* wrow = w + (size_t)row * Mc;
#pragma unroll
  for (int i = 0; i < 8; ++i) {
    ushort4 o;
    o.x = f2bf(fmaxf(z[i * 4 + 0] - tau, 0.f));
    o.y = f2bf(fmaxf(z[i * 4 + 1] - tau, 0.f));
    o.z = f2bf(fmaxf(z[i * 4 + 2] - tau, 0.f));
    o.w = f2bf(fmaxf(z[i * 4 + 3] - tau, 0.f));
    ((ushort4*)wrow)[i * 256 + tid] = o;
  }
}

// fc2 split-K reduce: out[r][c<1000] = p0 + p1 + bias
__global__ __launch_bounds__(256) void fc2_reduce(const float* __restrict__ p0,
                                                  const float* __restrict__ p1,
                                                  const float* __restrict__ bias,
                                                  float* __restrict__ out) {
  const int r = blockIdx.x, t = threadIdx.x;
  if (t < 250) {
    float4 a = ((const float4*)(p0 + (size_t)r * 1024))[t];
    float4 b = ((const float4*)(p1 + (size_t)r * 1024))[t];
    float4 c = ((const float4*)bias)[t];
    float4 o;
    o.x = a.x + b.x + c.x; o.y = a.y + b.y + c.y;
    o.z = a.z + b.z + c.z; o.w = a.w + b.w + c.w;
    ((float4*)(out + (size_t)r * 1000))[t] = o;
  }
}

// ---------------- GEMM 128x128 (m97 structure) ----------------
// EPI 3: plain bf16 (ldc). EPI 4: f32 partial (ldc); blockIdx.z selects K-split.
template <int EPI>
__global__ __launch_bounds__(256, 2) void gemm_bt(
    const unsigned short* __restrict__ A, const unsigned short* __restrict__ Bt,
    float* __restrict__ Cf, unsigned short* __restrict__ Cb,
    int M, int N, int K, int lda, int ldb, int ldc, size_t pstride) {
  __shared__ __align__(16) unsigned short Al[128 * 32];
  __shared__ __align__(16) unsigned short Bl[128 * 32];

  const size_t koff = (size_t)blockIdx.z * K;
  A += koff; Bt += koff;
  Cf += (size_t)blockIdx.z * pstride;

  const int tid = threadIdx.x;
  const int wave = tid >> 6;
  const int lane = tid & 63;
  const int bm = blockIdx.y * 128;
  const int bn = blockIdx.x * 128;
  const int wr = (wave >> 1) * 64;
  const int wc = (wave & 1) * 64;

  f32x4 acc[4][4] = {};

  const int srow = tid >> 2;
  const int scol = (tid & 3) * 8;
  const unsigned short* Ag = A + (size_t)(bm + srow) * lda + scol;
  const unsigned short* Bg = Bt + (size_t)(bn + srow) * ldb + scol;
  char* Alb = (char*)Al + wave * 1024;
  char* Blb = (char*)Bl + wave * 1024;

  const int fr = lane & 15;
  const int kq = lane >> 4;
  const unsigned short* Ard = Al + (wr + fr) * 32 + kq * 8;
  const unsigned short* Brd = Bl + (wc + fr) * 32 + kq * 8;

  for (int kt = 0; kt < K; kt += 32) {
    gload16(Ag + kt, Alb);
    gload16(Ag + kt + (size_t)64 * lda, Alb + 4096);
    gload16(Bg + kt, Blb);
    gload16(Bg + kt + (size_t)64 * ldb, Blb + 4096);
    __syncthreads();
    bf16x8 af[4], bfr[4];
#pragma unroll
    for (int m = 0; m < 4; ++m) af[m] = *(const bf16x8*)(Ard + m * 16 * 32);
#pragma unroll
    for (int n = 0; n < 4; ++n) bfr[n] = *(const bf16x8*)(Brd + n * 16 * 32);
#pragma unroll
    for (int m = 0; m < 4; ++m)
#pragma unroll
      for (int n = 0; n < 4; ++n)
        acc[m][n] = __builtin_amdgcn_mfma_f32_16x16x32_bf16(af[m], bfr[n], acc[m][n], 0, 0, 0);
    __syncthreads();
  }

  const int fq = lane >> 4;
#pragma unroll
  for (int m = 0; m < 4; ++m) {
    const int row0 = bm + wr + m * 16 + fq * 4;
#pragma unroll
    for (int n = 0; n < 4; ++n) {
      const int col = bn + wc + n * 16 + fr;
#pragma unroll
      for (int r = 0; r < 4; ++r) {
        float v = acc[m][n][r];
        if constexpr (EPI == 3) {
          Cb[(size_t)(row0 + r) * ldc + col] = f2bf(v);
        } else {
          Cf[(size_t)(row0 + r) * ldc + col] = v;
        }
      }
    }
  }
}

// ---------------- GEMM 256x256, BK=64, 8-wave, 4-phase, deep prefetch (region-safe) --
// Compile-time dbuf (K-loop unrolled x2). Tile kt+2 staged during tile kt into buf:
//   ph2: B(kt+2) both halves  — after ph1's last B read of tile kt
//   ph3: A(kt+2) both halves  — after ph2's last A read of tile kt
// vmcnt(8) at ph3 drains exactly tile kt+1 (its 8 loads are the oldest in the
// FIFO), whose youngest load was issued at ph3 of kt-1 -> ~4 phases of latency
// cover. WAR pattern identical to the proven round-6 schedule (stages into buf
// only at ph2/ph3, each >=1 barrier + MFMA-consumption after the region's last
// read). Tail: vmcnt(0) when kt+2 >= NT.
// EPI 1: +bias relu bf16. EPI 2: plain bf16.
template <int EPI>
__global__ __launch_bounds__(512, 1) void gemm256(
    const unsigned short* __restrict__ A, const unsigned short* __restrict__ Bt,
    const float* __restrict__ bias, unsigned short* __restrict__ Cb,
    int M, int N, int K, int lda, int ldc) {
  __shared__ __align__(16) unsigned short lds[2][2][256 * 64];  // 128 KiB

  const int tid = threadIdx.x;
  const int wid = tid >> 6;
  const int lane = tid & 63;
  const int wr = wid >> 2;      // 0..1  (128-row band)
  const int wc = wid & 3;       // 0..3  (64-col band)
  const int fr = lane & 15;
  const int kq = lane >> 4;

  // bijective XCD swizzle (m204)
  const int nx = gridDim.x;
  const int nwg = nx * gridDim.y;
  const int bid = blockIdx.y * nx + blockIdx.x;
  const int q = nwg >> 3, r8 = nwg & 7;
  const int xcd = bid & 7, idx = bid >> 3;
  const int wg = (xcd < r8 ? xcd * (q + 1) : r8 * (q + 1) + (xcd - r8) * q) + idx;
  const int bn = (wg % nx) * 256;
  const int bm = (wg / nx) * 256;

  const int NT = K >> 6;   // assumed even (K multiple of 128)

  const int st_r = tid >> 3;
  const int st_x = (tid & 7) << 4;
  const int colb = st_x ^ ((st_r & 7) << 4);
  const unsigned short* gbase[2][2][2];
#pragma unroll
  for (int mat = 0; mat < 2; ++mat)
#pragma unroll
    for (int half = 0; half < 2; ++half)
#pragma unroll
      for (int iss = 0; iss < 2; ++iss) {
        const int row = half * 128 + iss * 64 + st_r;
        gbase[mat][half][iss] =
            (mat ? Bt + (size_t)(bn + row) * K : A + (size_t)(bm + row) * lda) + (colb >> 1);
      }
  const int widb = wid << 10;

  auto stage = [&](auto dbufc, int mat, int half, int kt) {
    constexpr int dbuf = decltype(dbufc)::value;
#pragma unroll
    for (int iss = 0; iss < 2; ++iss) {
      const unsigned short* g = gbase[mat][half][iss] + ((size_t)kt << 6);
      char* l = (char*)&lds[dbuf][mat][0] + (half * 2 + iss) * 8192 + widb;
      gload16(g, l);
    }
  };

  const int swz = (fr & 7) << 4;
  const int arow = (wr * 128 + fr) * 128;
  const int brow = (wc * 64 + fr) * 128;
  const int col0 = (kq * 16) ^ swz;
  const int col1 = (64 + kq * 16) ^ swz;
  auto rdA = [&](auto bufc, int mh, int m, int kk) -> bf16x8 {
    constexpr int buf = decltype(bufc)::value;
    const int off = arow + mh * 8192 + m * 2048 + (kk ? col1 : col0);
    return *(const bf16x8*)((const char*)&lds[buf][0][0] + off);
  };
  auto rdB = [&](auto bufc, int nh, int n, int kk) -> bf16x8 {
    constexpr int buf = decltype(bufc)::value;
    const int off = brow + nh * 4096 + n * 2048 + (kk ? col1 : col0);
    return *(const bf16x8*)((const char*)&lds[buf][1][0] + off);
  };

  f32x4 acc[8][4] = {};
  bf16x8 a[4][2], b0[2][2], b1[2][2];

  // ---- prologue: stage tiles 0 and 1 fully; vmcnt(8) -> tile 0 landed
  stage(IC<0>{}, 1, 0, 0);
  stage(IC<0>{}, 0, 0, 0);
  stage(IC<0>{}, 1, 1, 0);
  stage(IC<0>{}, 0, 1, 0);
  if (NT > 1) {
    stage(IC<1>{}, 1, 0, 1);
    stage(IC<1>{}, 0, 0, 1);
    stage(IC<1>{}, 1, 1, 1);
    stage(IC<1>{}, 0, 1, 1);
    asm volatile("s_waitcnt vmcnt(8)" ::: "memory");
  } else {
    asm volatile("s_waitcnt vmcnt(0)" ::: "memory");
  }
  __builtin_amdgcn_sched_barrier(0);
  __builtin_amdgcn_s_barrier();
  __builtin_amdgcn_sched_barrier(0);

  auto ktile = [&](auto bufc, int kt) {
    constexpr int buf = decltype(bufc)::value;
    IC<buf> B_;

    // ===== ph0: read A0+B0(buf); MFMA quad(0,0); no staging
#pragma unroll
    for (int m = 0; m < 4; ++m) {
      a[m][0] = rdA(B_, 0, m, 0);
      a[m][1] = rdA(B_, 0, m, 1);
    }
#pragma unroll
    for (int n = 0; n < 2; ++n) {
      b0[n][0] = rdB(B_, 0, n, 0);
      b0[n][1] = rdB(B_, 0, n, 1);
    }
    __builtin_amdgcn_s_barrier();
    __builtin_amdgcn_s_setprio(1);
#pragma unroll
    for (int m = 0; m < 4; ++m)
#pragma unroll
      for (int n = 0; n < 2; ++n)
#pragma unroll
        for (int kk = 0; kk < 2; ++kk)
          acc[m][n] = __builtin_amdgcn_mfma_f32_16x16x32_bf16(a[m][kk], b0[n][kk], acc[m][n], 0, 0, 0);
    __builtin_amdgcn_s_setprio(0);
    __builtin_amdgcn_s_barrier();
    __builtin_amdgcn_sched_barrier(0);

    // ===== ph1: read B1(buf); MFMA quad(0,1); no staging
#pragma unroll
    for (int n = 0; n < 2; ++n) {
      b1[n][0] = rdB(B_, 1, n, 0);
      b1[n][1] = rdB(B_, 1, n, 1);
    }
    __builtin_amdgcn_s_barrier();
    __builtin_amdgcn_s_setprio(1);
#pragma unroll
    for (int m = 0; m < 4; ++m)
#pragma unroll
      for (int n = 0; n < 2; ++n)
#pragma unroll
        for (int kk = 0; kk < 2; ++kk)
          acc[m][n + 2] = __builtin_amdgcn_mfma_f32_16x16x32_bf16(a[m][kk], b1[n][kk], acc[m][n + 2], 0, 0, 0);
    __builtin_amdgcn_s_setprio(0);
    __builtin_amdgcn_s_barrier();
    __builtin_amdgcn_sched_barrier(0);

    // ===== ph2: read A1(buf); stage B(kt+2 -> buf) both halves; MFMA quad(1,1)
    //        (B's last in-tile reads were ph1, consumed by ph1's MFMA before its barrier)
#pragma unroll
    for (int m = 0; m < 4; ++m) {
      a[m][0] = rdA(B_, 1, m, 0);
      a[m][1] = rdA(B_, 1, m, 1);
    }
    if (kt + 2 < NT) {
      stage(B_, 1, 0, kt + 2);
      stage(B_, 1, 1, kt + 2);
    }
    __builtin_amdgcn_s_barrier();
    __builtin_amdgcn_s_setprio(1);
#pragma unroll
    for (int m = 0; m < 4; ++m)
#pragma unroll
      for (int n = 0; n < 2; ++n)
#pragma unroll
        for (int kk = 0; kk < 2; ++kk)
          acc[m + 4][n + 2] = __builtin_amdgcn_mfma_f32_16x16x32_bf16(a[m][kk], b1[n][kk], acc[m + 4][n + 2], 0, 0, 0);
    __builtin_amdgcn_s_setprio(0);
    __builtin_amdgcn_s_barrier();
    __builtin_amdgcn_sched_barrier(0);

    // ===== ph3: stage A(kt+2 -> buf) both halves; vmcnt(8) -> tile kt+1 landed;
    //            MFMA quad(1,0)   (A's last in-tile reads were ph2)
    if (kt + 2 < NT) {
      stage(B_, 0, 0, kt + 2);
      stage(B_, 0, 1, kt + 2);
      asm volatile("s_waitcnt vmcnt(8)" ::: "memory");
    } else {
      asm volatile("s_waitcnt vmcnt(0)" ::: "memory");
    }
    __builtin_amdgcn_sched_barrier(0);
    __builtin_amdgcn_s_barrier();
    __builtin_amdgcn_s_setprio(1);
#pragma unroll
    for (int m = 0; m < 4; ++m)
#pragma unroll
      for (int n = 0; n < 2; ++n)
#pragma unroll
        for (int kk = 0; kk < 2; ++kk)
          acc[m + 4][n] = __builtin_amdgcn_mfma_f32_16x16x32_bf16(a[m][kk], b0[n][kk], acc[m + 4][n], 0, 0, 0);
    __builtin_amdgcn_s_setprio(0);
    __builtin_amdgcn_s_barrier();
    __builtin_amdgcn_sched_barrier(0);
  };

  for (int kt = 0; kt < NT; kt += 2) {
    ktile(IC<0>{}, kt);
    ktile(IC<1>{}, kt + 1);
  }

  // ---- epilogue
  const int fq = lane >> 4;
#pragma unroll
  for (int m = 0; m < 8; ++m) {
    const int row0 = bm + wr * 128 + m * 16 + fq * 4;
#pragma unroll
    for (int n = 0; n < 4; ++n) {
      const int col = bn + wc * 64 + n * 16 + fr;
#pragma unroll
      for (int r = 0; r < 4; ++r) {
        float v = acc[m][n][r];
        if constexpr (EPI == 1) {
          v = fmaxf(v + bias[col], 0.0f);
          Cb[(size_t)(row0 + r) * ldc + col] = f2bf(v);
        } else {
          Cb[(size_t)(row0 + r) * ldc + col] = f2bf(v);
        }
      }
    }
  }
}

// ---------------- launch ----------------
extern "C" void kernel_launch(void* const* d_in, const int* in_sizes, int n_in,
                              void* d_out, int out_size, void* d_ws, size_t ws_size,
                              hipStream_t stream) {
  const float* enc  = (const float*)d_in[0];
  const float* mem  = (const float*)d_in[1];
  const float* fw1  = (const float*)d_in[2];
  const float* fb1  = (const float*)d_in[3];
  const float* fw2  = (const float*)d_in[4];
  const float* fb2  = (const float*)d_in[5];
  float* out = (float*)d_out;

  const int B = 4096, M = 8192, D = 2048, HID = 8192, OUT = 1000, OUTP = 1024;

  char* p = (char*)d_ws;
  auto alloc = [&](size_t bytes) {
    char* r = p;
    p += (bytes + 255) & ~(size_t)255;
    return r;
  };
  unsigned short* memB = (unsigned short*)alloc((size_t)M * D * 2);        // 32 MB
  unsigned short* memT = (unsigned short*)alloc((size_t)D * M * 2);        // 32 MB
  unsigned short* w1   = (unsigned short*)alloc((size_t)HID * 2 * D * 2);  // 64 MB
  unsigned short* w2   = (unsigned short*)alloc((size_t)OUTP * HID * 2);   // 16 MB
  unsigned short* wts  = (unsigned short*)alloc((size_t)B * M * 2);        // 64 MB
  unsigned short* fin  = (unsigned short*)alloc((size_t)B * 2 * D * 2);    // 32 MB
  float* rs            = (float*)alloc((size_t)B * 4);
  float* cs            = (float*)alloc((size_t)M * 4);
  float* p0            = (float*)alloc((size_t)B * OUTP * 4);              // 16 MB
  float* p1            = (float*)alloc((size_t)B * OUTP * 4);              // 16 MB
  unsigned short* hid  = (unsigned short*)alloc((size_t)B * HID * 2);      // 64 MB
  unsigned short* simb = hid;  // alias: simb dead before fc1 writes hid

  // prep
  conv_norm_row<<<B, 256, 0, stream>>>(enc, fin, rs, D, 2 * D);
  conv_norm_row<<<M, 256, 0, stream>>>(mem, memB, cs, D, D);
  transpose_bb<<<dim3(D / 64, M / 64), 256, 0, stream>>>(memB, memT, M, D);
  convert2_bf16<<<2048, 256, 0, stream>>>(fw1, w1, (long)HID * 2 * D / 4,
                                          fw2, w2, (long)OUT * HID / 4);

  // raw sims = bf16(enc) @ bf16(mem)^T  [B, M] -> bf16 (norms folded into sparsemax)
  gemm256<2><<<dim3(M / 256, B / 256), 512, 0, stream>>>(fin, memB, nullptr, simb,
                                                         B, M, D, 2 * D, M);
  // sparsemax(z * rs * cs) -> dense bf16 weights
  sparsemax_scaled<<<B, 256, 0, stream>>>(simb, rs, cs, wts, M);
  // fin[:, D:2D) = wts @ mem  (dense, fused bf16 store)
  gemm_bt<3><<<dim3(D / 128, B / 128), 256, 0, stream>>>(wts, memT, nullptr, fin + D,
                                                         B, D, M, M, M, 2 * D, 0);
  // hidden = relu(fin @ fc1_w^T + b1) -> bf16
  gemm256<1><<<dim3(HID / 256, B / 256), 512, 0, stream>>>(fin, w1, fb1, hid,
                                                           B, HID, 2 * D, 2 * D, HID);
  // out = hidden @ fc2_w^T + b2 : split-K=2 in ONE launch (grid.z), then reduce
  gemm_bt<4><<<dim3(OUTP / 128, B / 128, 2), 256, 0, stream>>>(
      hid, w2, p0, nullptr, B, OUTP, HID / 2, HID, HID, OUTP, (size_t)B * OUTP);
  fc2_reduce<<<B, 256, 0, stream>>>(p0, p1, fb2, out);
}

// Round 9
// 850.345 us; speedup vs baseline: 1.1164x; 1.0250x over previous
//
#include <hip/hip_runtime.h>
#include <stdint.h>

typedef __attribute__((ext_vector_type(8))) __bf16 bf16x8;
typedef __attribute__((ext_vector_type(4))) float f32x4;

template <int V> struct IC { static constexpr int value = V; };

__device__ __forceinline__ unsigned short f2bf(float f) {
  unsigned u = __float_as_uint(f);
  u += 0x7FFFu + ((u >> 16) & 1u);
  return (unsigned short)(u >> 16);
}
__device__ __forceinline__ float bf2f(unsigned short u) {
  return __uint_as_float((unsigned)u << 16);
}

__device__ __forceinline__ void gload16(const void* g, void* lds) {
  __builtin_amdgcn_global_load_lds((const __attribute__((address_space(1))) void*)g,
                                   (__attribute__((address_space(3))) void*)lds, 16, 0, 0);
}

// ---------------- prep kernels ----------------

// merged: rows [0,Brows) -> enc path (write y1 stride ld1, rs); rows [Brows,..) -> mem path.
__global__ __launch_bounds__(256) void conv_norm_both(
    const float* __restrict__ enc, const float* __restrict__ mem,
    unsigned short* __restrict__ y1, unsigned short* __restrict__ y2,
    float* __restrict__ rs, float* __restrict__ cs,
    int Brows, int cols, int ld1) {
  const int row = blockIdx.x;
  const float* x;
  unsigned short* y;
  float* outp;
  if (row < Brows) {
    x = enc + (size_t)row * cols;
    y = y1 + (size_t)row * ld1;
    outp = rs + row;
  } else {
    const int r2 = row - Brows;
    x = mem + (size_t)r2 * cols;
    y = y2 + (size_t)r2 * cols;
    outp = cs + r2;
  }
  const float4* x4 = (const float4*)x;
  ushort4* y4 = (ushort4*)y;
  const int n4 = cols >> 2;
  float s = 0.f;
  for (int i = threadIdx.x; i < n4; i += 256) {
    float4 t = x4[i];
    s += t.x * t.x + t.y * t.y + t.z * t.z + t.w * t.w;
    ushort4 o;
    o.x = f2bf(t.x); o.y = f2bf(t.y); o.z = f2bf(t.z); o.w = f2bf(t.w);
    y4[i] = o;
  }
#pragma unroll
  for (int o = 32; o >= 1; o >>= 1) s += __shfl_xor(s, o, 64);
  __shared__ float red[4];
  if ((threadIdx.x & 63) == 0) red[threadIdx.x >> 6] = s;
  __syncthreads();
  if (threadIdx.x == 0) {
    const float tot = red[0] + red[1] + red[2] + red[3];
    *outp = 1.0f / sqrtf(tot + 1e-6f);
  }
}

// two f32->bf16 converts in one launch (n in float4 units)
__global__ __launch_bounds__(256) void convert2_bf16(const float* __restrict__ x1,
                                                     unsigned short* __restrict__ y1, long n1,
                                                     const float* __restrict__ x2,
                                                     unsigned short* __restrict__ y2, long n2) {
  long i = (long)blockIdx.x * 256 + threadIdx.x;
  const long stride = (long)gridDim.x * 256;
  const long tot = n1 + n2;
  for (; i < tot; i += stride) {
    const float4* src; ushort4* dst; long j;
    if (i < n1) { src = (const float4*)x1; dst = (ushort4*)y1; j = i; }
    else        { src = (const float4*)x2; dst = (ushort4*)y2; j = i - n1; }
    float4 t = src[j];
    ushort4 o;
    o.x = f2bf(t.x); o.y = f2bf(t.y); o.z = f2bf(t.z); o.w = f2bf(t.w);
    dst[j] = o;
  }
}

// bf16 [R][C] -> bf16 [C][R], 64x64 tiles, ushort4 both sides
__global__ __launch_bounds__(256) void transpose_bb(const unsigned short* __restrict__ x,
                                                    unsigned short* __restrict__ y,
                                                    int R, int C) {
  __shared__ unsigned short tile[64][65];
  const int r0 = blockIdx.y * 64;
  const int c0 = blockIdx.x * 64;
#pragma unroll
  for (int i = 0; i < 4; ++i) {
    int lin = i * 256 + threadIdx.x;
    int r = lin >> 4, c4 = (lin & 15) * 4;
    ushort4 v = *(const ushort4*)(x + (size_t)(r0 + r) * C + c0 + c4);
    tile[r][c4 + 0] = v.x; tile[r][c4 + 1] = v.y;
    tile[r][c4 + 2] = v.z; tile[r][c4 + 3] = v.w;
  }
  __syncthreads();
#pragma unroll
  for (int i = 0; i < 4; ++i) {
    int lin = i * 256 + threadIdx.x;
    int c = lin >> 4, r4 = (lin & 15) * 4;
    ushort4 o;
    o.x = tile[r4 + 0][c]; o.y = tile[r4 + 1][c];
    o.z = tile[r4 + 2][c]; o.w = tile[r4 + 3][c];
    *(ushort4*)(y + (size_t)(c0 + c) * R + r0 + r4) = o;
  }
}

// ---------------- sparsemax (scaled raw sims -> dense bf16 weights) ----------------
// 18 bisection iters, ONE barrier per iter (ping-pong red buffers; WAR-safe:
// slot it&1 is read between barriers it and it+1, and re-written only after
// passing barrier it+1).
__global__ __launch_bounds__(256) void sparsemax_scaled(
    const unsigned short* __restrict__ simb, const float* __restrict__ rs,
    const float* __restrict__ cs, unsigned short* __restrict__ w, int Mc) {
  const int row = blockIdx.x;
  const int tid = threadIdx.x;
  const float r = rs[row];
  const ushort4* z4 = (const ushort4*)(simb + (size_t)row * Mc);
  const float4* c4 = (const float4*)cs;
  float z[32];
#pragma unroll
  for (int i = 0; i < 8; ++i) {
    ushort4 v = z4[i * 256 + tid];
    float4 c = c4[i * 256 + tid];
    z[i * 4 + 0] = bf2f(v.x) * r * c.x;
    z[i * 4 + 1] = bf2f(v.y) * r * c.y;
    z[i * 4 + 2] = bf2f(v.z) * r * c.z;
    z[i * 4 + 3] = bf2f(v.w) * r * c.w;
  }
  float mx = z[0];
#pragma unroll
  for (int j = 1; j < 32; ++j) mx = fmaxf(mx, z[j]);
#pragma unroll
  for (int o = 32; o >= 1; o >>= 1) mx = fmaxf(mx, __shfl_xor(mx, o, 64));
  __shared__ float redm[4];
  __shared__ float red[2][4];
  const int wv = tid >> 6, ln = tid & 63;
  if (ln == 0) redm[wv] = mx;
  __syncthreads();
  mx = fmaxf(fmaxf(redm[0], redm[1]), fmaxf(redm[2], redm[3]));

  float lo = mx - 1.0f, hi = mx;
  for (int it = 0; it < 18; ++it) {
    const float tau = 0.5f * (lo + hi);
    float s = 0.f;
#pragma unroll
    for (int j = 0; j < 32; ++j) s += fmaxf(z[j] - tau, 0.f);
#pragma unroll
    for (int o = 32; o >= 1; o >>= 1) s += __shfl_xor(s, o, 64);
    if (ln == 0) red[it & 1][wv] = s;
    __syncthreads();
    s = red[it & 1][0] + red[it & 1][1] + red[it & 1][2] + red[it & 1][3];
    if (s > 1.0f) lo = tau; else hi = tau;
  }
  const float tau = 0.5f * (lo + hi);
  unsigned short* wrow = w + (size_t)row * Mc;
#pragma unroll
  for (int i = 0; i < 8; ++i) {
    ushort4 o;
    o.x = f2bf(fmaxf(z[i * 4 + 0] - tau, 0.f));
    o.y = f2bf(fmaxf(z[i * 4 + 1] - tau, 0.f));
    o.z = f2bf(fmaxf(z[i * 4 + 2] - tau, 0.f));
    o.w = f2bf(fmaxf(z[i * 4 + 3] - tau, 0.f));
    ((ushort4*)wrow)[i * 256 + tid] = o;
  }
}

// fc2 split-K reduce: out[r][c<1000] = p0 + p1 + bias
__global__ __launch_bounds__(256) void fc2_reduce(const float* __restrict__ p0,
                                                  const float* __restrict__ p1,
                                                  const float* __restrict__ bias,
                                                  float* __restrict__ out) {
  const int r = blockIdx.x, t = threadIdx.x;
  if (t < 250) {
    float4 a = ((const float4*)(p0 + (size_t)r * 1024))[t];
    float4 b = ((const float4*)(p1 + (size_t)r * 1024))[t];
    float4 c = ((const float4*)bias)[t];
    float4 o;
    o.x = a.x + b.x + c.x; o.y = a.y + b.y + c.y;
    o.z = a.z + b.z + c.z; o.w = a.w + b.w + c.w;
    ((float4*)(out + (size_t)r * 1000))[t] = o;
  }
}

// ---------------- GEMM 128x128 (m97 structure) ----------------
// EPI 3: plain bf16 (ldc). EPI 4: f32 partial (ldc); blockIdx.z selects K-split.
template <int EPI>
__global__ __launch_bounds__(256, 2) void gemm_bt(
    const unsigned short* __restrict__ A, const unsigned short* __restrict__ Bt,
    float* __restrict__ Cf, unsigned short* __restrict__ Cb,
    int M, int N, int K, int lda, int ldb, int ldc, size_t pstride) {
  __shared__ __align__(16) unsigned short Al[128 * 32];
  __shared__ __align__(16) unsigned short Bl[128 * 32];

  const size_t koff = (size_t)blockIdx.z * K;
  A += koff; Bt += koff;
  Cf += (size_t)blockIdx.z * pstride;

  const int tid = threadIdx.x;
  const int wave = tid >> 6;
  const int lane = tid & 63;
  const int bm = blockIdx.y * 128;
  const int bn = blockIdx.x * 128;
  const int wr = (wave >> 1) * 64;
  const int wc = (wave & 1) * 64;

  f32x4 acc[4][4] = {};

  const int srow = tid >> 2;
  const int scol = (tid & 3) * 8;
  const unsigned short* Ag = A + (size_t)(bm + srow) * lda + scol;
  const unsigned short* Bg = Bt + (size_t)(bn + srow) * ldb + scol;
  char* Alb = (char*)Al + wave * 1024;
  char* Blb = (char*)Bl + wave * 1024;

  const int fr = lane & 15;
  const int kq = lane >> 4;
  const unsigned short* Ard = Al + (wr + fr) * 32 + kq * 8;
  const unsigned short* Brd = Bl + (wc + fr) * 32 + kq * 8;

  for (int kt = 0; kt < K; kt += 32) {
    gload16(Ag + kt, Alb);
    gload16(Ag + kt + (size_t)64 * lda, Alb + 4096);
    gload16(Bg + kt, Blb);
    gload16(Bg + kt + (size_t)64 * ldb, Blb + 4096);
    __syncthreads();
    bf16x8 af[4], bfr[4];
#pragma unroll
    for (int m = 0; m < 4; ++m) af[m] = *(const bf16x8*)(Ard + m * 16 * 32);
#pragma unroll
    for (int n = 0; n < 4; ++n) bfr[n] = *(const bf16x8*)(Brd + n * 16 * 32);
#pragma unroll
    for (int m = 0; m < 4; ++m)
#pragma unroll
      for (int n = 0; n < 4; ++n)
        acc[m][n] = __builtin_amdgcn_mfma_f32_16x16x32_bf16(af[m], bfr[n], acc[m][n], 0, 0, 0);
    __syncthreads();
  }

  const int fq = lane >> 4;
#pragma unroll
  for (int m = 0; m < 4; ++m) {
    const int row0 = bm + wr + m * 16 + fq * 4;
#pragma unroll
    for (int n = 0; n < 4; ++n) {
      const int col = bn + wc + n * 16 + fr;
#pragma unroll
      for (int r = 0; r < 4; ++r) {
        float v = acc[m][n][r];
        if constexpr (EPI == 3) {
          Cb[(size_t)(row0 + r) * ldc + col] = f2bf(v);
        } else {
          Cf[(size_t)(row0 + r) * ldc + col] = v;
        }
      }
    }
  }
}

// ---------------- GEMM 256x256, BK=64, 8-wave, 4-phase (round-6 schedule, REVERT) ----
// Proven-best variant (47.0% MfmaUtil, 262 us fc1). Compile-time dbuf, dataflow
// LDS waits, stages: ph0 B1(kt+1,nbuf), ph1 A1(kt+1,nbuf), ph2 B0(kt+2,buf),
// ph3 A0(kt+2,buf) + vmcnt(4). DO NOT restructure further (5 variants plateau 44-47%).
// EPI 1: +bias relu bf16. EPI 2: plain bf16.
template <int EPI>
__global__ __launch_bounds__(512, 1) void gemm256(
    const unsigned short* __restrict__ A, const unsigned short* __restrict__ Bt,
    const float* __restrict__ bias, unsigned short* __restrict__ Cb,
    int M, int N, int K, int lda, int ldc) {
  __shared__ __align__(16) unsigned short lds[2][2][256 * 64];  // 128 KiB

  const int tid = threadIdx.x;
  const int wid = tid >> 6;
  const int lane = tid & 63;
  const int wr = wid >> 2;      // 0..1  (128-row band)
  const int wc = wid & 3;       // 0..3  (64-col band)
  const int fr = lane & 15;
  const int kq = lane >> 4;

  // bijective XCD swizzle (m204)
  const int nx = gridDim.x;
  const int nwg = nx * gridDim.y;
  const int bid = blockIdx.y * nx + blockIdx.x;
  const int q = nwg >> 3, r8 = nwg & 7;
  const int xcd = bid & 7, idx = bid >> 3;
  const int wg = (xcd < r8 ? xcd * (q + 1) : r8 * (q + 1) + (xcd - r8) * q) + idx;
  const int bn = (wg % nx) * 256;
  const int bm = (wg / nx) * 256;

  const int NT = K >> 6;   // assumed even (K multiple of 128)

  const int st_r = tid >> 3;
  const int st_x = (tid & 7) << 4;
  const int colb = st_x ^ ((st_r & 7) << 4);
  const unsigned short* gbase[2][2][2];
#pragma unroll
  for (int mat = 0; mat < 2; ++mat)
#pragma unroll
    for (int half = 0; half < 2; ++half)
#pragma unroll
      for (int iss = 0; iss < 2; ++iss) {
        const int row = half * 128 + iss * 64 + st_r;
        gbase[mat][half][iss] =
            (mat ? Bt + (size_t)(bn + row) * K : A + (size_t)(bm + row) * lda) + (colb >> 1);
      }
  const int widb = wid << 10;

  auto stage = [&](auto dbufc, int mat, int half, int kt) {
    constexpr int dbuf = decltype(dbufc)::value;
#pragma unroll
    for (int iss = 0; iss < 2; ++iss) {
      const unsigned short* g = gbase[mat][half][iss] + ((size_t)kt << 6);
      char* l = (char*)&lds[dbuf][mat][0] + (half * 2 + iss) * 8192 + widb;
      gload16(g, l);
    }
  };

  const int swz = (fr & 7) << 4;
  const int arow = (wr * 128 + fr) * 128;
  const int brow = (wc * 64 + fr) * 128;
  const int col0 = (kq * 16) ^ swz;
  const int col1 = (64 + kq * 16) ^ swz;
  auto rdA = [&](auto bufc, int mh, int m, int kk) -> bf16x8 {
    constexpr int buf = decltype(bufc)::value;
    const int off = arow + mh * 8192 + m * 2048 + (kk ? col1 : col0);
    return *(const bf16x8*)((const char*)&lds[buf][0][0] + off);
  };
  auto rdB = [&](auto bufc, int nh, int n, int kk) -> bf16x8 {
    constexpr int buf = decltype(bufc)::value;
    const int off = brow + nh * 4096 + n * 2048 + (kk ? col1 : col0);
    return *(const bf16x8*)((const char*)&lds[buf][1][0] + off);
  };

  f32x4 acc[8][4] = {};
  bf16x8 a[4][2], b0[2][2], b1[2][2];

  // ---- prologue: K-tile 0 (all 4 halves) + K-tile 1 (B0, A0)
  stage(IC<0>{}, 1, 0, 0);
  stage(IC<0>{}, 0, 0, 0);
  stage(IC<0>{}, 1, 1, 0);
  stage(IC<0>{}, 0, 1, 0);
  if (NT > 1) {
    stage(IC<1>{}, 1, 0, 1);
    stage(IC<1>{}, 0, 0, 1);
    asm volatile("s_waitcnt vmcnt(4)" ::: "memory");
  } else {
    asm volatile("s_waitcnt vmcnt(0)" ::: "memory");
  }
  __builtin_amdgcn_sched_barrier(0);
  __builtin_amdgcn_s_barrier();
  __builtin_amdgcn_sched_barrier(0);

  auto ktile = [&](auto bufc, int kt) {
    constexpr int buf = decltype(bufc)::value;
    constexpr int nbuf = buf ^ 1;
    IC<buf> B_; IC<nbuf> NB_;

    // ===== ph0: read A0+B0(buf); stage B1(kt+1); MFMA quad(0,0)
#pragma unroll
    for (int m = 0; m < 4; ++m) {
      a[m][0] = rdA(B_, 0, m, 0);
      a[m][1] = rdA(B_, 0, m, 1);
    }
#pragma unroll
    for (int n = 0; n < 2; ++n) {
      b0[n][0] = rdB(B_, 0, n, 0);
      b0[n][1] = rdB(B_, 0, n, 1);
    }
    if (kt + 1 < NT) stage(NB_, 1, 1, kt + 1);
    __builtin_amdgcn_s_barrier();
    __builtin_amdgcn_s_setprio(1);
#pragma unroll
    for (int m = 0; m < 4; ++m)
#pragma unroll
      for (int n = 0; n < 2; ++n)
#pragma unroll
        for (int kk = 0; kk < 2; ++kk)
          acc[m][n] = __builtin_amdgcn_mfma_f32_16x16x32_bf16(a[m][kk], b0[n][kk], acc[m][n], 0, 0, 0);
    __builtin_amdgcn_s_setprio(0);
    __builtin_amdgcn_s_barrier();
    __builtin_amdgcn_sched_barrier(0);

    // ===== ph1: read B1(buf); stage A1(kt+1); MFMA quad(0,1)
#pragma unroll
    for (int n = 0; n < 2; ++n) {
      b1[n][0] = rdB(B_, 1, n, 0);
      b1[n][1] = rdB(B_, 1, n, 1);
    }
    if (kt + 1 < NT) stage(NB_, 0, 1, kt + 1);
    __builtin_amdgcn_s_barrier();
    __builtin_amdgcn_s_setprio(1);
#pragma unroll
    for (int m = 0; m < 4; ++m)
#pragma unroll
      for (int n = 0; n < 2; ++n)
#pragma unroll
        for (int kk = 0; kk < 2; ++kk)
          acc[m][n + 2] = __builtin_amdgcn_mfma_f32_16x16x32_bf16(a[m][kk], b1[n][kk], acc[m][n + 2], 0, 0, 0);
    __builtin_amdgcn_s_setprio(0);
    __builtin_amdgcn_s_barrier();
    __builtin_amdgcn_sched_barrier(0);

    // ===== ph2: read A1(buf); stage B0(kt+2 -> buf); MFMA quad(1,1)
#pragma unroll
    for (int m = 0; m < 4; ++m) {
      a[m][0] = rdA(B_, 1, m, 0);
      a[m][1] = rdA(B_, 1, m, 1);
    }
    if (kt + 2 < NT) stage(B_, 1, 0, kt + 2);
    __builtin_amdgcn_s_barrier();
    __builtin_amdgcn_s_setprio(1);
#pragma unroll
    for (int m = 0; m < 4; ++m)
#pragma unroll
      for (int n = 0; n < 2; ++n)
#pragma unroll
        for (int kk = 0; kk < 2; ++kk)
          acc[m + 4][n + 2] = __builtin_amdgcn_mfma_f32_16x16x32_bf16(a[m][kk], b1[n][kk], acc[m + 4][n + 2], 0, 0, 0);
    __builtin_amdgcn_s_setprio(0);
    __builtin_amdgcn_s_barrier();
    __builtin_amdgcn_sched_barrier(0);

    // ===== ph3: stage A0(kt+2 -> buf); counted vmcnt; MFMA quad(1,0)
    if (kt + 2 < NT) {
      stage(B_, 0, 0, kt + 2);
      asm volatile("s_waitcnt vmcnt(4)" ::: "memory");
    } else {
      asm volatile("s_waitcnt vmcnt(0)" ::: "memory");
    }
    __builtin_amdgcn_sched_barrier(0);
    __builtin_amdgcn_s_barrier();
    __builtin_amdgcn_s_setprio(1);
#pragma unroll
    for (int m = 0; m < 4; ++m)
#pragma unroll
      for (int n = 0; n < 2; ++n)
#pragma unroll
        for (int kk = 0; kk < 2; ++kk)
          acc[m + 4][n] = __builtin_amdgcn_mfma_f32_16x16x32_bf16(a[m][kk], b0[n][kk], acc[m + 4][n], 0, 0, 0);
    __builtin_amdgcn_s_setprio(0);
    __builtin_amdgcn_s_barrier();
    __builtin_amdgcn_sched_barrier(0);
  };

  for (int kt = 0; kt < NT; kt += 2) {
    ktile(IC<0>{}, kt);
    ktile(IC<1>{}, kt + 1);
  }

  // ---- epilogue
  const int fq = lane >> 4;
#pragma unroll
  for (int m = 0; m < 8; ++m) {
    const int row0 = bm + wr * 128 + m * 16 + fq * 4;
#pragma unroll
    for (int n = 0; n < 4; ++n) {
      const int col = bn + wc * 64 + n * 16 + fr;
#pragma unroll
      for (int r = 0; r < 4; ++r) {
        float v = acc[m][n][r];
        if constexpr (EPI == 1) {
          v = fmaxf(v + bias[col], 0.0f);
          Cb[(size_t)(row0 + r) * ldc + col] = f2bf(v);
        } else {
          Cb[(size_t)(row0 + r) * ldc + col] = f2bf(v);
        }
      }
    }
  }
}

// ---------------- launch ----------------
extern "C" void kernel_launch(void* const* d_in, const int* in_sizes, int n_in,
                              void* d_out, int out_size, void* d_ws, size_t ws_size,
                              hipStream_t stream) {
  const float* enc  = (const float*)d_in[0];
  const float* mem  = (const float*)d_in[1];
  const float* fw1  = (const float*)d_in[2];
  const float* fb1  = (const float*)d_in[3];
  const float* fw2  = (const float*)d_in[4];
  const float* fb2  = (const float*)d_in[5];
  float* out = (float*)d_out;

  const int B = 4096, M = 8192, D = 2048, HID = 8192, OUT = 1000, OUTP = 1024;

  char* p = (char*)d_ws;
  auto alloc = [&](size_t bytes) {
    char* r = p;
    p += (bytes + 255) & ~(size_t)255;
    return r;
  };
  unsigned short* memB = (unsigned short*)alloc((size_t)M * D * 2);        // 32 MB
  unsigned short* memT = (unsigned short*)alloc((size_t)D * M * 2);        // 32 MB
  unsigned short* w1   = (unsigned short*)alloc((size_t)HID * 2 * D * 2);  // 64 MB
  unsigned short* w2   = (unsigned short*)alloc((size_t)OUTP * HID * 2);   // 16 MB
  unsigned short* wts  = (unsigned short*)alloc((size_t)B * M * 2);        // 64 MB
  unsigned short* fin  = (unsigned short*)alloc((size_t)B * 2 * D * 2);    // 32 MB
  float* rs            = (float*)alloc((size_t)B * 4);
  float* cs            = (float*)alloc((size_t)M * 4);
  float* p0            = (float*)alloc((size_t)B * OUTP * 4);              // 16 MB
  float* p1            = (float*)alloc((size_t)B * OUTP * 4);              // 16 MB
  unsigned short* hid  = (unsigned short*)alloc((size_t)B * HID * 2);      // 64 MB
  unsigned short* simb = hid;  // alias: simb dead before fc1 writes hid

  // prep: merged norms+casts, transpose, weight casts
  conv_norm_both<<<B + M, 256, 0, stream>>>(enc, mem, fin, memB, rs, cs, B, D, 2 * D);
  transpose_bb<<<dim3(D / 64, M / 64), 256, 0, stream>>>(memB, memT, M, D);
  convert2_bf16<<<2048, 256, 0, stream>>>(fw1, w1, (long)HID * 2 * D / 4,
                                          fw2, w2, (long)OUT * HID / 4);

  // raw sims = bf16(enc) @ bf16(mem)^T  [B, M] -> bf16 (norms folded into sparsemax)
  gemm256<2><<<dim3(M / 256, B / 256), 512, 0, stream>>>(fin, memB, nullptr, simb,
                                                         B, M, D, 2 * D, M);
  // sparsemax(z * rs * cs) -> dense bf16 weights
  sparsemax_scaled<<<B, 256, 0, stream>>>(simb, rs, cs, wts, M);
  // fin[:, D:2D) = wts @ mem  (dense, fused bf16 store)
  gemm_bt<3><<<dim3(D / 128, B / 128), 256, 0, stream>>>(wts, memT, nullptr, fin + D,
                                                         B, D, M, M, M, 2 * D, 0);
  // hidden = relu(fin @ fc1_w^T + b1) -> bf16
  gemm256<1><<<dim3(HID / 256, B / 256), 512, 0, stream>>>(fin, w1, fb1, hid,
                                                           B, HID, 2 * D, 2 * D, HID);
  // out = hidden @ fc2_w^T + b2 : split-K=2 in ONE launch (grid.z), then reduce
  gemm_bt<4><<<dim3(OUTP / 128, B / 128, 2), 256, 0, stream>>>(
      hid, w2, p0, nullptr, B, OUTP, HID / 2, HID, HID, OUTP, (size_t)B * OUTP);
  fc2_reduce<<<B, 256, 0, stream>>>(p0, p1, fb2, out);
}

// Round 10
// 792.473 us; speedup vs baseline: 1.1979x; 1.0730x over previous
//
#include <hip/hip_runtime.h>
#include <stdint.h>

typedef __attribute__((ext_vector_type(8))) __bf16 bf16x8;
typedef __attribute__((ext_vector_type(4))) float f32x4;

template <int V> struct IC { static constexpr int value = V; };

__device__ __forceinline__ unsigned short f2bf(float f) {
  unsigned u = __float_as_uint(f);
  u += 0x7FFFu + ((u >> 16) & 1u);
  return (unsigned short)(u >> 16);
}
__device__ __forceinline__ float bf2f(unsigned short u) {
  return __uint_as_float((unsigned)u << 16);
}

__device__ __forceinline__ void gload16(const void* g, void* lds) {
  __builtin_amdgcn_global_load_lds((const __attribute__((address_space(1))) void*)g,
                                   (__attribute__((address_space(3))) void*)lds, 16, 0, 0);
}

// ---------------- merged prep: row norms (enc+mem) + weight converts ----------------
__global__ __launch_bounds__(256) void prep_all(
    const float* __restrict__ enc, const float* __restrict__ mem,
    const float* __restrict__ fw1, const float* __restrict__ fw2,
    unsigned short* __restrict__ fin, unsigned short* __restrict__ memB,
    unsigned short* __restrict__ w1, unsigned short* __restrict__ w2,
    float* __restrict__ rs, float* __restrict__ cs,
    int Brows, int Mrows, int cols, int ld1, long n41, long n42) {
  const int blk = blockIdx.x;
  const int nrm = Brows + Mrows;
  if (blk < nrm) {
    const float* x;
    unsigned short* y;
    float* outp;
    if (blk < Brows) {
      x = enc + (size_t)blk * cols;
      y = fin + (size_t)blk * ld1;
      outp = rs + blk;
    } else {
      const int r2 = blk - Brows;
      x = mem + (size_t)r2 * cols;
      y = memB + (size_t)r2 * cols;
      outp = cs + r2;
    }
    const float4* x4 = (const float4*)x;
    ushort4* y4 = (ushort4*)y;
    const int n4 = cols >> 2;
    float s = 0.f;
    for (int i = threadIdx.x; i < n4; i += 256) {
      float4 t = x4[i];
      s += t.x * t.x + t.y * t.y + t.z * t.z + t.w * t.w;
      ushort4 o;
      o.x = f2bf(t.x); o.y = f2bf(t.y); o.z = f2bf(t.z); o.w = f2bf(t.w);
      y4[i] = o;
    }
#pragma unroll
    for (int o = 32; o >= 1; o >>= 1) s += __shfl_xor(s, o, 64);
    __shared__ float red[4];
    if ((threadIdx.x & 63) == 0) red[threadIdx.x >> 6] = s;
    __syncthreads();
    if (threadIdx.x == 0) {
      const float tot = red[0] + red[1] + red[2] + red[3];
      *outp = 1.0f / sqrtf(tot + 1e-6f);
    }
  } else {
    const int cb = blk - nrm;  // 0..2047
    long i = (long)cb * 256 + threadIdx.x;
    const long stride = 2048L * 256;
    const long tot = n41 + n42;
    for (; i < tot; i += stride) {
      const float4* src; ushort4* dst; long j;
      if (i < n41) { src = (const float4*)fw1; dst = (ushort4*)w1; j = i; }
      else         { src = (const float4*)fw2; dst = (ushort4*)w2; j = i - n41; }
      float4 t = src[j];
      ushort4 o;
      o.x = f2bf(t.x); o.y = f2bf(t.y); o.z = f2bf(t.z); o.w = f2bf(t.w);
      dst[j] = o;
    }
  }
}

// bf16 [R][C] -> bf16 [C][R], 64x64 tiles, ushort4 both sides
__global__ __launch_bounds__(256) void transpose_bb(const unsigned short* __restrict__ x,
                                                    unsigned short* __restrict__ y,
                                                    int R, int C) {
  __shared__ unsigned short tile[64][65];
  const int r0 = blockIdx.y * 64;
  const int c0 = blockIdx.x * 64;
#pragma unroll
  for (int i = 0; i < 4; ++i) {
    int lin = i * 256 + threadIdx.x;
    int r = lin >> 4, c4 = (lin & 15) * 4;
    ushort4 v = *(const ushort4*)(x + (size_t)(r0 + r) * C + c0 + c4);
    tile[r][c4 + 0] = v.x; tile[r][c4 + 1] = v.y;
    tile[r][c4 + 2] = v.z; tile[r][c4 + 3] = v.w;
  }
  __syncthreads();
#pragma unroll
  for (int i = 0; i < 4; ++i) {
    int lin = i * 256 + threadIdx.x;
    int c = lin >> 4, r4 = (lin & 15) * 4;
    ushort4 o;
    o.x = tile[r4 + 0][c]; o.y = tile[r4 + 1][c];
    o.z = tile[r4 + 2][c]; o.w = tile[r4 + 3][c];
    *(ushort4*)(y + (size_t)(c0 + c) * R + r0 + r4) = o;
  }
}

// ---------------- sparsemax (scaled raw sims -> dense bf16 weights) ----------------
__global__ __launch_bounds__(256) void sparsemax_scaled(
    const unsigned short* __restrict__ simb, const float* __restrict__ rs,
    const float* __restrict__ cs, unsigned short* __restrict__ w, int Mc) {
  const int row = blockIdx.x;
  const int tid = threadIdx.x;
  const float r = rs[row];
  const ushort4* z4 = (const ushort4*)(simb + (size_t)row * Mc);
  const float4* c4 = (const float4*)cs;
  float z[32];
#pragma unroll
  for (int i = 0; i < 8; ++i) {
    ushort4 v = z4[i * 256 + tid];
    float4 c = c4[i * 256 + tid];
    z[i * 4 + 0] = bf2f(v.x) * r * c.x;
    z[i * 4 + 1] = bf2f(v.y) * r * c.y;
    z[i * 4 + 2] = bf2f(v.z) * r * c.z;
    z[i * 4 + 3] = bf2f(v.w) * r * c.w;
  }
  float mx = z[0];
#pragma unroll
  for (int j = 1; j < 32; ++j) mx = fmaxf(mx, z[j]);
#pragma unroll
  for (int o = 32; o >= 1; o >>= 1) mx = fmaxf(mx, __shfl_xor(mx, o, 64));
  __shared__ float redm[4];
  __shared__ float red[2][4];
  const int wv = tid >> 6, ln = tid & 63;
  if (ln == 0) redm[wv] = mx;
  __syncthreads();
  mx = fmaxf(fmaxf(redm[0], redm[1]), fmaxf(redm[2], redm[3]));

  float lo = mx - 1.0f, hi = mx;
  for (int it = 0; it < 18; ++it) {
    const float tau = 0.5f * (lo + hi);
    float s = 0.f;
#pragma unroll
    for (int j = 0; j < 32; ++j) s += fmaxf(z[j] - tau, 0.f);
#pragma unroll
    for (int o = 32; o >= 1; o >>= 1) s += __shfl_xor(s, o, 64);
    if (ln == 0) red[it & 1][wv] = s;
    __syncthreads();
    s = red[it & 1][0] + red[it & 1][1] + red[it & 1][2] + red[it & 1][3];
    if (s > 1.0f) lo = tau; else hi = tau;
  }
  const float tau = 0.5f * (lo + hi);
  unsigned short* wrow = w + (size_t)row * Mc;
#pragma unroll
  for (int i = 0; i < 8; ++i) {
    ushort4 o;
    o.x = f2bf(fmaxf(z[i * 4 + 0] - tau, 0.f));
    o.y = f2bf(fmaxf(z[i * 4 + 1] - tau, 0.f));
    o.z = f2bf(fmaxf(z[i * 4 + 2] - tau, 0.f));
    o.w = f2bf(fmaxf(z[i * 4 + 3] - tau, 0.f));
    ((ushort4*)wrow)[i * 256 + tid] = o;
  }
}

// fc2 split-K reduce: out[r][c<1000] = p0 + p1 + bias
__global__ __launch_bounds__(256) void fc2_reduce(const float* __restrict__ p0,
                                                  const float* __restrict__ p1,
                                                  const float* __restrict__ bias,
                                                  float* __restrict__ out) {
  const int r = blockIdx.x, t = threadIdx.x;
  if (t < 250) {
    float4 a = ((const float4*)(p0 + (size_t)r * 1024))[t];
    float4 b = ((const float4*)(p1 + (size_t)r * 1024))[t];
    float4 c = ((const float4*)bias)[t];
    float4 o;
    o.x = a.x + b.x + c.x; o.y = a.y + b.y + c.y;
    o.z = a.z + b.z + c.z; o.w = a.w + b.w + c.w;
    ((float4*)(out + (size_t)r * 1000))[t] = o;
  }
}

// ---------------- GEMM 256xBN, BK=64, 8-wave, 4-phase (round-6 schedule) -----------
// C[M,N] = A[M,K](stride lda) * Bt[N,K]^T(stride ldb). bf16 in, f32 acc.
// Template BN in {256,128}: BN=256 reduces EXACTLY to the proven round-6 kernel
// (wc*64, nh*32, 2 B-frags, B-half=2 gloads, vmcnt(4)). BN=128: 1 B-frag,
// B-half=1 gload, vmcnt(3). Schedule frozen — do not restructure (5-variant plateau).
// EPI 1: +bias relu bf16. EPI 2: plain bf16. EPI 4: f32 partial, blockIdx.z K-split.
template <int EPI, int BN>
__global__ __launch_bounds__(512, 1) void gemm256(
    const unsigned short* __restrict__ A, const unsigned short* __restrict__ Bt,
    const float* __restrict__ bias, unsigned short* __restrict__ Cb,
    float* __restrict__ Cf, int M, int N, int K, int lda, int ldb, int ldc,
    size_t pstride) {
  constexpr int NFR = BN / 128;        // B n-frags per nh; B gloads per half
  __shared__ __align__(16) unsigned short ldsA[2][256 * 64];
  __shared__ __align__(16) unsigned short ldsB[2][BN * 64];

  // K-split (EPI 4); z=0 no-op otherwise
  const size_t koff = (size_t)blockIdx.z * K;
  A += koff; Bt += koff;
  Cf += (size_t)blockIdx.z * pstride;

  const int tid = threadIdx.x;
  const int wid = tid >> 6;
  const int lane = tid & 63;
  const int wr = wid >> 2;      // 0..1  (128-row band)
  const int wc = wid & 3;       // 0..3  (BN/4-col band)
  const int fr = lane & 15;
  const int kq = lane >> 4;

  // bijective XCD swizzle (m204)
  const int nx = gridDim.x;
  const int nwg = nx * gridDim.y;
  const int bid = blockIdx.y * nx + blockIdx.x;
  const int q = nwg >> 3, r8 = nwg & 7;
  const int xcd = bid & 7, idx = bid >> 3;
  const int wg = (xcd < r8 ? xcd * (q + 1) : r8 * (q + 1) + (xcd - r8) * q) + idx;
  const int bn = (wg % nx) * BN;
  const int bm = (wg / nx) * 256;

  const int NT = K >> 6;   // assumed even

  const int st_r = tid >> 3;
  const int st_x = (tid & 7) << 4;
  const int colb = st_x ^ ((st_r & 7) << 4);
  const unsigned short* gbA[2][2];
  const unsigned short* gbB[2][NFR];
#pragma unroll
  for (int half = 0; half < 2; ++half) {
#pragma unroll
    for (int iss = 0; iss < 2; ++iss) {
      const int row = half * 128 + iss * 64 + st_r;
      gbA[half][iss] = A + (size_t)(bm + row) * lda + (colb >> 1);
    }
#pragma unroll
    for (int iss = 0; iss < NFR; ++iss) {
      const int row = half * (BN / 2) + iss * 64 + st_r;
      gbB[half][iss] = Bt + (size_t)(bn + row) * ldb + (colb >> 1);
    }
  }
  const int widb = wid << 10;

  auto stageA = [&](auto dbufc, int half, int kt) {
    constexpr int dbuf = decltype(dbufc)::value;
#pragma unroll
    for (int iss = 0; iss < 2; ++iss) {
      const unsigned short* g = gbA[half][iss] + ((size_t)kt << 6);
      char* l = (char*)&ldsA[dbuf][0] + (half * 2 + iss) * 8192 + widb;
      gload16(g, l);
    }
  };
  auto stageB = [&](auto dbufc, int half, int kt) {
    constexpr int dbuf = decltype(dbufc)::value;
#pragma unroll
    for (int iss = 0; iss < NFR; ++iss) {
      const unsigned short* g = gbB[half][iss] + ((size_t)kt << 6);
      char* l = (char*)&ldsB[dbuf][0] + (half * NFR + iss) * 8192 + widb;
      gload16(g, l);
    }
  };

  const int swz = (fr & 7) << 4;
  const int arow = (wr * 128 + fr) * 128;
  const int brow = (wc * (BN / 4) + fr) * 128;
  const int col0 = (kq * 16) ^ swz;
  const int col1 = (64 + kq * 16) ^ swz;
  auto rdA = [&](auto bufc, int mh, int m, int kk) -> bf16x8 {
    constexpr int buf = decltype(bufc)::value;
    const int off = arow + mh * 8192 + m * 2048 + (kk ? col1 : col0);
    return *(const bf16x8*)((const char*)&ldsA[buf][0] + off);
  };
  auto rdB = [&](auto bufc, int nh, int n, int kk) -> bf16x8 {
    constexpr int buf = decltype(bufc)::value;
    const int off = brow + (nh * (BN / 8) + n * 16) * 128 + (kk ? col1 : col0);
    return *(const bf16x8*)((const char*)&ldsB[buf][0] + off);
  };

  f32x4 acc[8][2 * NFR] = {};
  bf16x8 a[4][2], b0[NFR][2], b1[NFR][2];

  // ---- prologue: tile 0 fully + tile 1 (B half0, A half0)
  stageB(IC<0>{}, 0, 0);
  stageA(IC<0>{}, 0, 0);
  stageB(IC<0>{}, 1, 0);
  stageA(IC<0>{}, 1, 0);
  if (NT > 1) {
    stageB(IC<1>{}, 0, 1);
    stageA(IC<1>{}, 0, 1);
    if constexpr (NFR == 2) asm volatile("s_waitcnt vmcnt(4)" ::: "memory");
    else                    asm volatile("s_waitcnt vmcnt(3)" ::: "memory");
  } else {
    asm volatile("s_waitcnt vmcnt(0)" ::: "memory");
  }
  __builtin_amdgcn_sched_barrier(0);
  __builtin_amdgcn_s_barrier();
  __builtin_amdgcn_sched_barrier(0);

  auto ktile = [&](auto bufc, int kt) {
    constexpr int buf = decltype(bufc)::value;
    constexpr int nbuf = buf ^ 1;
    IC<buf> B_; IC<nbuf> NB_;

    // ===== ph0: read A(mh0)+B(nh0); stage B half1(kt+1,nbuf); MFMA quad(0,0)
#pragma unroll
    for (int m = 0; m < 4; ++m) {
      a[m][0] = rdA(B_, 0, m, 0);
      a[m][1] = rdA(B_, 0, m, 1);
    }
#pragma unroll
    for (int n = 0; n < NFR; ++n) {
      b0[n][0] = rdB(B_, 0, n, 0);
      b0[n][1] = rdB(B_, 0, n, 1);
    }
    if (kt + 1 < NT) stageB(NB_, 1, kt + 1);
    __builtin_amdgcn_s_barrier();
    __builtin_amdgcn_s_setprio(1);
#pragma unroll
    for (int m = 0; m < 4; ++m)
#pragma unroll
      for (int n = 0; n < NFR; ++n)
#pragma unroll
        for (int kk = 0; kk < 2; ++kk)
          acc[m][n] = __builtin_amdgcn_mfma_f32_16x16x32_bf16(a[m][kk], b0[n][kk], acc[m][n], 0, 0, 0);
    __builtin_amdgcn_s_setprio(0);
    __builtin_amdgcn_s_barrier();
    __builtin_amdgcn_sched_barrier(0);

    // ===== ph1: read B(nh1); stage A half1(kt+1,nbuf); MFMA quad(0,1)
#pragma unroll
    for (int n = 0; n < NFR; ++n) {
      b1[n][0] = rdB(B_, 1, n, 0);
      b1[n][1] = rdB(B_, 1, n, 1);
    }
    if (kt + 1 < NT) stageA(NB_, 1, kt + 1);
    __builtin_amdgcn_s_barrier();
    __builtin_amdgcn_s_setprio(1);
#pragma unroll
    for (int m = 0; m < 4; ++m)
#pragma unroll
      for (int n = 0; n < NFR; ++n)
#pragma unroll
        for (int kk = 0; kk < 2; ++kk)
          acc[m][NFR + n] = __builtin_amdgcn_mfma_f32_16x16x32_bf16(a[m][kk], b1[n][kk], acc[m][NFR + n], 0, 0, 0);
    __builtin_amdgcn_s_setprio(0);
    __builtin_amdgcn_s_barrier();
    __builtin_amdgcn_sched_barrier(0);

    // ===== ph2: read A(mh1); stage B half0(kt+2,buf) [all B reads done at ph1]; MFMA quad(1,1)
#pragma unroll
    for (int m = 0; m < 4; ++m) {
      a[m][0] = rdA(B_, 1, m, 0);
      a[m][1] = rdA(B_, 1, m, 1);
    }
    if (kt + 2 < NT) stageB(B_, 0, kt + 2);
    __builtin_amdgcn_s_barrier();
    __builtin_amdgcn_s_setprio(1);
#pragma unroll
    for (int m = 0; m < 4; ++m)
#pragma unroll
      for (int n = 0; n < NFR; ++n)
#pragma unroll
        for (int kk = 0; kk < 2; ++kk)
          acc[m + 4][NFR + n] = __builtin_amdgcn_mfma_f32_16x16x32_bf16(a[m][kk], b1[n][kk], acc[m + 4][NFR + n], 0, 0, 0);
    __builtin_amdgcn_s_setprio(0);
    __builtin_amdgcn_s_barrier();
    __builtin_amdgcn_sched_barrier(0);

    // ===== ph3: stage A half0(kt+2,buf) [all A reads done at ph2]; counted vmcnt; MFMA quad(1,0)
    if (kt + 2 < NT) {
      stageA(B_, 0, kt + 2);
      if constexpr (NFR == 2) asm volatile("s_waitcnt vmcnt(4)" ::: "memory");
      else                    asm volatile("s_waitcnt vmcnt(3)" ::: "memory");
    } else {
      asm volatile("s_waitcnt vmcnt(0)" ::: "memory");
    }
    __builtin_amdgcn_sched_barrier(0);
    __builtin_amdgcn_s_barrier();
    __builtin_amdgcn_s_setprio(1);
#pragma unroll
    for (int m = 0; m < 4; ++m)
#pragma unroll
      for (int n = 0; n < NFR; ++n)
#pragma unroll
        for (int kk = 0; kk < 2; ++kk)
          acc[m + 4][n] = __builtin_amdgcn_mfma_f32_16x16x32_bf16(a[m][kk], b0[n][kk], acc[m + 4][n], 0, 0, 0);
    __builtin_amdgcn_s_setprio(0);
    __builtin_amdgcn_s_barrier();
    __builtin_amdgcn_sched_barrier(0);
  };

  for (int kt = 0; kt < NT; kt += 2) {
    ktile(IC<0>{}, kt);
    ktile(IC<1>{}, kt + 1);
  }

  // ---- epilogue
  const int fq = lane >> 4;
#pragma unroll
  for (int m = 0; m < 8; ++m) {
    const int row0 = bm + wr * 128 + m * 16 + fq * 4;
#pragma unroll
    for (int nh = 0; nh < 2; ++nh)
#pragma unroll
      for (int n = 0; n < NFR; ++n) {
        const int col = bn + wc * (BN / 4) + nh * (BN / 8) + n * 16 + fr;
        const int slot = nh * NFR + n;
#pragma unroll
        for (int r = 0; r < 4; ++r) {
          float v = acc[m][slot][r];
          if constexpr (EPI == 1) {
            v = fmaxf(v + bias[col], 0.0f);
            Cb[(size_t)(row0 + r) * ldc + col] = f2bf(v);
          } else if constexpr (EPI == 2) {
            Cb[(size_t)(row0 + r) * ldc + col] = f2bf(v);
          } else {
            Cf[(size_t)(row0 + r) * ldc + col] = v;
          }
        }
      }
  }
}

// ---------------- launch ----------------
extern "C" void kernel_launch(void* const* d_in, const int* in_sizes, int n_in,
                              void* d_out, int out_size, void* d_ws, size_t ws_size,
                              hipStream_t stream) {
  const float* enc  = (const float*)d_in[0];
  const float* mem  = (const float*)d_in[1];
  const float* fw1  = (const float*)d_in[2];
  const float* fb1  = (const float*)d_in[3];
  const float* fw2  = (const float*)d_in[4];
  const float* fb2  = (const float*)d_in[5];
  float* out = (float*)d_out;

  const int B = 4096, M = 8192, D = 2048, HID = 8192, OUT = 1000, OUTP = 1024;

  char* p = (char*)d_ws;
  auto alloc = [&](size_t bytes) {
    char* r = p;
    p += (bytes + 255) & ~(size_t)255;
    return r;
  };
  unsigned short* memB = (unsigned short*)alloc((size_t)M * D * 2);        // 32 MB
  unsigned short* memT = (unsigned short*)alloc((size_t)D * M * 2);        // 32 MB
  unsigned short* w1   = (unsigned short*)alloc((size_t)HID * 2 * D * 2);  // 64 MB
  unsigned short* w2   = (unsigned short*)alloc((size_t)OUTP * HID * 2);   // 16 MB
  unsigned short* wts  = (unsigned short*)alloc((size_t)B * M * 2);        // 64 MB
  unsigned short* fin  = (unsigned short*)alloc((size_t)B * 2 * D * 2);    // 32 MB
  float* rs            = (float*)alloc((size_t)B * 4);
  float* cs            = (float*)alloc((size_t)M * 4);
  float* pp            = (float*)alloc((size_t)2 * B * OUTP * 4);          // 32 MB partials
  unsigned short* hid  = (unsigned short*)alloc((size_t)B * HID * 2);      // 64 MB
  unsigned short* simb = hid;  // alias: simb dead before fc1 writes hid

  // prep: norms + casts + weight converts in ONE launch
  prep_all<<<B + M + 2048, 256, 0, stream>>>(enc, mem, fw1, fw2, fin, memB, w1, w2,
                                             rs, cs, B, M, D, 2 * D,
                                             (long)HID * 2 * D / 4, (long)OUT * HID / 4);
  transpose_bb<<<dim3(D / 64, M / 64), 256, 0, stream>>>(memB, memT, M, D);

  // raw sims = bf16(enc) @ bf16(mem)^T  [B, M] -> bf16 (norms folded into sparsemax)
  gemm256<2, 256><<<dim3(M / 256, B / 256), 512, 0, stream>>>(
      fin, memB, nullptr, simb, nullptr, B, M, D, 2 * D, D, M, 0);
  // sparsemax(z * rs * cs) -> dense bf16 weights
  sparsemax_scaled<<<B, 256, 0, stream>>>(simb, rs, cs, wts, M);
  // fin[:, D:2D) = wts @ mem  (BN=128: grid 16x16 = 256 blocks = 1/CU)
  gemm256<2, 128><<<dim3(D / 128, B / 256), 512, 0, stream>>>(
      wts, memT, nullptr, fin + D, nullptr, B, D, M, M, M, 2 * D, 0);
  // hidden = relu(fin @ fc1_w^T + b1) -> bf16
  gemm256<1, 256><<<dim3(HID / 256, B / 256), 512, 0, stream>>>(
      fin, w1, fb1, hid, nullptr, B, HID, 2 * D, 2 * D, 2 * D, HID, 0);
  // out partials: hidden @ fc2_w^T, split-K=2 via grid.z (8x16x2 = 256 blocks)
  gemm256<4, 128><<<dim3(OUTP / 128, B / 256, 2), 512, 0, stream>>>(
      hid, w2, nullptr, nullptr, pp, B, OUTP, HID / 2, HID, HID, OUTP,
      (size_t)B * OUTP);
  fc2_reduce<<<B, 256, 0, stream>>>(pp, pp + (size_t)B * OUTP, fb2, out);
}

// Round 11
// 745.699 us; speedup vs baseline: 1.2730x; 1.0627x over previous
//
#include <hip/hip_runtime.h>
#include <stdint.h>

typedef __attribute__((ext_vector_type(8))) __bf16 bf16x8;
typedef __attribute__((ext_vector_type(4))) float f32x4;

template <int V> struct IC { static constexpr int value = V; };

__device__ __forceinline__ unsigned short f2bf(float f) {
  unsigned u = __float_as_uint(f);
  u += 0x7FFFu + ((u >> 16) & 1u);
  return (unsigned short)(u >> 16);
}
__device__ __forceinline__ float bf2f(unsigned short u) {
  return __uint_as_float((unsigned)u << 16);
}

__device__ __forceinline__ void gload16(const void* g, void* lds) {
  __builtin_amdgcn_global_load_lds((const __attribute__((address_space(1))) void*)g,
                                   (__attribute__((address_space(3))) void*)lds, 16, 0, 0);
}

// ---------------- merged prep: row norms (enc+mem) + weight converts ----------------
__global__ __launch_bounds__(256) void prep_all(
    const float* __restrict__ enc, const float* __restrict__ mem,
    const float* __restrict__ fw1, const float* __restrict__ fw2,
    unsigned short* __restrict__ fin, unsigned short* __restrict__ memB,
    unsigned short* __restrict__ w1, unsigned short* __restrict__ w2,
    float* __restrict__ rs, float* __restrict__ cs,
    int Brows, int Mrows, int cols, int ld1, long n41, long n42) {
  const int blk = blockIdx.x;
  const int nrm = Brows + Mrows;
  if (blk < nrm) {
    const float* x;
    unsigned short* y;
    float* outp;
    if (blk < Brows) {
      x = enc + (size_t)blk * cols;
      y = fin + (size_t)blk * ld1;
      outp = rs + blk;
    } else {
      const int r2 = blk - Brows;
      x = mem + (size_t)r2 * cols;
      y = memB + (size_t)r2 * cols;
      outp = cs + r2;
    }
    const float4* x4 = (const float4*)x;
    ushort4* y4 = (ushort4*)y;
    const int n4 = cols >> 2;
    float s = 0.f;
    for (int i = threadIdx.x; i < n4; i += 256) {
      float4 t = x4[i];
      s += t.x * t.x + t.y * t.y + t.z * t.z + t.w * t.w;
      ushort4 o;
      o.x = f2bf(t.x); o.y = f2bf(t.y); o.z = f2bf(t.z); o.w = f2bf(t.w);
      y4[i] = o;
    }
#pragma unroll
    for (int o = 32; o >= 1; o >>= 1) s += __shfl_xor(s, o, 64);
    __shared__ float red[4];
    if ((threadIdx.x & 63) == 0) red[threadIdx.x >> 6] = s;
    __syncthreads();
    if (threadIdx.x == 0) {
      const float tot = red[0] + red[1] + red[2] + red[3];
      *outp = 1.0f / sqrtf(tot + 1e-6f);
    }
  } else {
    const int cb = blk - nrm;  // 0..2047
    long i = (long)cb * 256 + threadIdx.x;
    const long stride = 2048L * 256;
    const long tot = n41 + n42;
    for (; i < tot; i += stride) {
      const float4* src; ushort4* dst; long j;
      if (i < n41) { src = (const float4*)fw1; dst = (ushort4*)w1; j = i; }
      else         { src = (const float4*)fw2; dst = (ushort4*)w2; j = i - n41; }
      float4 t = src[j];
      ushort4 o;
      o.x = f2bf(t.x); o.y = f2bf(t.y); o.z = f2bf(t.z); o.w = f2bf(t.w);
      dst[j] = o;
    }
  }
}

// bf16 [R][C] -> bf16 [C][R], 64x64 tiles, ushort4 both sides
__global__ __launch_bounds__(256) void transpose_bb(const unsigned short* __restrict__ x,
                                                    unsigned short* __restrict__ y,
                                                    int R, int C) {
  __shared__ unsigned short tile[64][65];
  const int r0 = blockIdx.y * 64;
  const int c0 = blockIdx.x * 64;
#pragma unroll
  for (int i = 0; i < 4; ++i) {
    int lin = i * 256 + threadIdx.x;
    int r = lin >> 4, c4 = (lin & 15) * 4;
    ushort4 v = *(const ushort4*)(x + (size_t)(r0 + r) * C + c0 + c4);
    tile[r][c4 + 0] = v.x; tile[r][c4 + 1] = v.y;
    tile[r][c4 + 2] = v.z; tile[r][c4 + 3] = v.w;
  }
  __syncthreads();
#pragma unroll
  for (int i = 0; i < 4; ++i) {
    int lin = i * 256 + threadIdx.x;
    int c = lin >> 4, r4 = (lin & 15) * 4;
    ushort4 o;
    o.x = tile[r4 + 0][c]; o.y = tile[r4 + 1][c];
    o.z = tile[r4 + 2][c]; o.w = tile[r4 + 3][c];
    *(ushort4*)(y + (size_t)(c0 + c) * R + r0 + r4) = o;
  }
}

// ---------------- sparsemax (scaled raw sims -> dense bf16 weights) ----------------
__global__ __launch_bounds__(256) void sparsemax_scaled(
    const unsigned short* __restrict__ simb, const float* __restrict__ rs,
    const float* __restrict__ cs, unsigned short* __restrict__ w, int Mc) {
  const int row = blockIdx.x;
  const int tid = threadIdx.x;
  const float r = rs[row];
  const ushort4* z4 = (const ushort4*)(simb + (size_t)row * Mc);
  const float4* c4 = (const float4*)cs;
  float z[32];
#pragma unroll
  for (int i = 0; i < 8; ++i) {
    ushort4 v = z4[i * 256 + tid];
    float4 c = c4[i * 256 + tid];
    z[i * 4 + 0] = bf2f(v.x) * r * c.x;
    z[i * 4 + 1] = bf2f(v.y) * r * c.y;
    z[i * 4 + 2] = bf2f(v.z) * r * c.z;
    z[i * 4 + 3] = bf2f(v.w) * r * c.w;
  }
  float mx = z[0];
#pragma unroll
  for (int j = 1; j < 32; ++j) mx = fmaxf(mx, z[j]);
#pragma unroll
  for (int o = 32; o >= 1; o >>= 1) mx = fmaxf(mx, __shfl_xor(mx, o, 64));
  __shared__ float redm[4];
  __shared__ float red[2][4];
  const int wv = tid >> 6, ln = tid & 63;
  if (ln == 0) redm[wv] = mx;
  __syncthreads();
  mx = fmaxf(fmaxf(redm[0], redm[1]), fmaxf(redm[2], redm[3]));

  float lo = mx - 1.0f, hi = mx;
  for (int it = 0; it < 18; ++it) {
    const float tau = 0.5f * (lo + hi);
    float s = 0.f;
#pragma unroll
    for (int j = 0; j < 32; ++j) s += fmaxf(z[j] - tau, 0.f);
#pragma unroll
    for (int o = 32; o >= 1; o >>= 1) s += __shfl_xor(s, o, 64);
    if (ln == 0) red[it & 1][wv] = s;
    __syncthreads();
    s = red[it & 1][0] + red[it & 1][1] + red[it & 1][2] + red[it & 1][3];
    if (s > 1.0f) lo = tau; else hi = tau;
  }
  const float tau = 0.5f * (lo + hi);
  unsigned short* wrow = w + (size_t)row * Mc;
#pragma unroll
  for (int i = 0; i < 8; ++i) {
    ushort4 o;
    o.x = f2bf(fmaxf(z[i * 4 + 0] - tau, 0.f));
    o.y = f2bf(fmaxf(z[i * 4 + 1] - tau, 0.f));
    o.z = f2bf(fmaxf(z[i * 4 + 2] - tau, 0.f));
    o.w = f2bf(fmaxf(z[i * 4 + 3] - tau, 0.f));
    ((ushort4*)wrow)[i * 256 + tid] = o;
  }
}

// fc2 split-K reduce: out[r][c<1000] = p0 + p1 + bias
__global__ __launch_bounds__(256) void fc2_reduce(const float* __restrict__ p0,
                                                  const float* __restrict__ p1,
                                                  const float* __restrict__ bias,
                                                  float* __restrict__ out) {
  const int r = blockIdx.x, t = threadIdx.x;
  if (t < 250) {
    float4 a = ((const float4*)(p0 + (size_t)r * 1024))[t];
    float4 b = ((const float4*)(p1 + (size_t)r * 1024))[t];
    float4 c = ((const float4*)bias)[t];
    float4 o;
    o.x = a.x + b.x + c.x; o.y = a.y + b.y + c.y;
    o.z = a.z + b.z + c.z; o.w = a.w + b.w + c.w;
    ((float4*)(out + (size_t)r * 1000))[t] = o;
  }
}

// ---------------- GEMM 256x256, BK=64, 8-wave, 4-phase (round-6/9 schedule, FROZEN) --
// Byte-identical restore of the round-9 kernel (262 us fc1 @ 47.0% MfmaUtil).
// EPI 1: +bias relu bf16. EPI 2: plain bf16.
template <int EPI>
__global__ __launch_bounds__(512, 1) void gemm256(
    const unsigned short* __restrict__ A, const unsigned short* __restrict__ Bt,
    const float* __restrict__ bias, unsigned short* __restrict__ Cb,
    int M, int N, int K, int lda, int ldc) {
  __shared__ __align__(16) unsigned short lds[2][2][256 * 64];  // 128 KiB

  const int tid = threadIdx.x;
  const int wid = tid >> 6;
  const int lane = tid & 63;
  const int wr = wid >> 2;      // 0..1  (128-row band)
  const int wc = wid & 3;       // 0..3  (64-col band)
  const int fr = lane & 15;
  const int kq = lane >> 4;

  // bijective XCD swizzle (m204)
  const int nx = gridDim.x;
  const int nwg = nx * gridDim.y;
  const int bid = blockIdx.y * nx + blockIdx.x;
  const int q = nwg >> 3, r8 = nwg & 7;
  const int xcd = bid & 7, idx = bid >> 3;
  const int wg = (xcd < r8 ? xcd * (q + 1) : r8 * (q + 1) + (xcd - r8) * q) + idx;
  const int bn = (wg % nx) * 256;
  const int bm = (wg / nx) * 256;

  const int NT = K >> 6;   // assumed even (K multiple of 128)

  const int st_r = tid >> 3;
  const int st_x = (tid & 7) << 4;
  const int colb = st_x ^ ((st_r & 7) << 4);
  const unsigned short* gbase[2][2][2];
#pragma unroll
  for (int mat = 0; mat < 2; ++mat)
#pragma unroll
    for (int half = 0; half < 2; ++half)
#pragma unroll
      for (int iss = 0; iss < 2; ++iss) {
        const int row = half * 128 + iss * 64 + st_r;
        gbase[mat][half][iss] =
            (mat ? Bt + (size_t)(bn + row) * K : A + (size_t)(bm + row) * lda) + (colb >> 1);
      }
  const int widb = wid << 10;

  auto stage = [&](auto dbufc, int mat, int half, int kt) {
    constexpr int dbuf = decltype(dbufc)::value;
#pragma unroll
    for (int iss = 0; iss < 2; ++iss) {
      const unsigned short* g = gbase[mat][half][iss] + ((size_t)kt << 6);
      char* l = (char*)&lds[dbuf][mat][0] + (half * 2 + iss) * 8192 + widb;
      gload16(g, l);
    }
  };

  const int swz = (fr & 7) << 4;
  const int arow = (wr * 128 + fr) * 128;
  const int brow = (wc * 64 + fr) * 128;
  const int col0 = (kq * 16) ^ swz;
  const int col1 = (64 + kq * 16) ^ swz;
  auto rdA = [&](auto bufc, int mh, int m, int kk) -> bf16x8 {
    constexpr int buf = decltype(bufc)::value;
    const int off = arow + mh * 8192 + m * 2048 + (kk ? col1 : col0);
    return *(const bf16x8*)((const char*)&lds[buf][0][0] + off);
  };
  auto rdB = [&](auto bufc, int nh, int n, int kk) -> bf16x8 {
    constexpr int buf = decltype(bufc)::value;
    const int off = brow + nh * 4096 + n * 2048 + (kk ? col1 : col0);
    return *(const bf16x8*)((const char*)&lds[buf][1][0] + off);
  };

  f32x4 acc[8][4] = {};
  bf16x8 a[4][2], b0[2][2], b1[2][2];

  // ---- prologue: K-tile 0 (all 4 halves) + K-tile 1 (B0, A0)
  stage(IC<0>{}, 1, 0, 0);
  stage(IC<0>{}, 0, 0, 0);
  stage(IC<0>{}, 1, 1, 0);
  stage(IC<0>{}, 0, 1, 0);
  if (NT > 1) {
    stage(IC<1>{}, 1, 0, 1);
    stage(IC<1>{}, 0, 0, 1);
    asm volatile("s_waitcnt vmcnt(4)" ::: "memory");
  } else {
    asm volatile("s_waitcnt vmcnt(0)" ::: "memory");
  }
  __builtin_amdgcn_sched_barrier(0);
  __builtin_amdgcn_s_barrier();
  __builtin_amdgcn_sched_barrier(0);

  auto ktile = [&](auto bufc, int kt) {
    constexpr int buf = decltype(bufc)::value;
    constexpr int nbuf = buf ^ 1;
    IC<buf> B_; IC<nbuf> NB_;

    // ===== ph0: read A0+B0(buf); stage B1(kt+1); MFMA quad(0,0)
#pragma unroll
    for (int m = 0; m < 4; ++m) {
      a[m][0] = rdA(B_, 0, m, 0);
      a[m][1] = rdA(B_, 0, m, 1);
    }
#pragma unroll
    for (int n = 0; n < 2; ++n) {
      b0[n][0] = rdB(B_, 0, n, 0);
      b0[n][1] = rdB(B_, 0, n, 1);
    }
    if (kt + 1 < NT) stage(NB_, 1, 1, kt + 1);
    __builtin_amdgcn_s_barrier();
    __builtin_amdgcn_s_setprio(1);
#pragma unroll
    for (int m = 0; m < 4; ++m)
#pragma unroll
      for (int n = 0; n < 2; ++n)
#pragma unroll
        for (int kk = 0; kk < 2; ++kk)
          acc[m][n] = __builtin_amdgcn_mfma_f32_16x16x32_bf16(a[m][kk], b0[n][kk], acc[m][n], 0, 0, 0);
    __builtin_amdgcn_s_setprio(0);
    __builtin_amdgcn_s_barrier();
    __builtin_amdgcn_sched_barrier(0);

    // ===== ph1: read B1(buf); stage A1(kt+1); MFMA quad(0,1)
#pragma unroll
    for (int n = 0; n < 2; ++n) {
      b1[n][0] = rdB(B_, 1, n, 0);
      b1[n][1] = rdB(B_, 1, n, 1);
    }
    if (kt + 1 < NT) stage(NB_, 0, 1, kt + 1);
    __builtin_amdgcn_s_barrier();
    __builtin_amdgcn_s_setprio(1);
#pragma unroll
    for (int m = 0; m < 4; ++m)
#pragma unroll
      for (int n = 0; n < 2; ++n)
#pragma unroll
        for (int kk = 0; kk < 2; ++kk)
          acc[m][n + 2] = __builtin_amdgcn_mfma_f32_16x16x32_bf16(a[m][kk], b1[n][kk], acc[m][n + 2], 0, 0, 0);
    __builtin_amdgcn_s_setprio(0);
    __builtin_amdgcn_s_barrier();
    __builtin_amdgcn_sched_barrier(0);

    // ===== ph2: read A1(buf); stage B0(kt+2 -> buf); MFMA quad(1,1)
#pragma unroll
    for (int m = 0; m < 4; ++m) {
      a[m][0] = rdA(B_, 1, m, 0);
      a[m][1] = rdA(B_, 1, m, 1);
    }
    if (kt + 2 < NT) stage(B_, 1, 0, kt + 2);
    __builtin_amdgcn_s_barrier();
    __builtin_amdgcn_s_setprio(1);
#pragma unroll
    for (int m = 0; m < 4; ++m)
#pragma unroll
      for (int n = 0; n < 2; ++n)
#pragma unroll
        for (int kk = 0; kk < 2; ++kk)
          acc[m + 4][n + 2] = __builtin_amdgcn_mfma_f32_16x16x32_bf16(a[m][kk], b1[n][kk], acc[m + 4][n + 2], 0, 0, 0);
    __builtin_amdgcn_s_setprio(0);
    __builtin_amdgcn_s_barrier();
    __builtin_amdgcn_sched_barrier(0);

    // ===== ph3: stage A0(kt+2 -> buf); counted vmcnt; MFMA quad(1,0)
    if (kt + 2 < NT) {
      stage(B_, 0, 0, kt + 2);
      asm volatile("s_waitcnt vmcnt(4)" ::: "memory");
    } else {
      asm volatile("s_waitcnt vmcnt(0)" ::: "memory");
    }
    __builtin_amdgcn_sched_barrier(0);
    __builtin_amdgcn_s_barrier();
    __builtin_amdgcn_s_setprio(1);
#pragma unroll
    for (int m = 0; m < 4; ++m)
#pragma unroll
      for (int n = 0; n < 2; ++n)
#pragma unroll
        for (int kk = 0; kk < 2; ++kk)
          acc[m + 4][n] = __builtin_amdgcn_mfma_f32_16x16x32_bf16(a[m][kk], b0[n][kk], acc[m + 4][n], 0, 0, 0);
    __builtin_amdgcn_s_setprio(0);
    __builtin_amdgcn_s_barrier();
    __builtin_amdgcn_sched_barrier(0);
  };

  for (int kt = 0; kt < NT; kt += 2) {
    ktile(IC<0>{}, kt);
    ktile(IC<1>{}, kt + 1);
  }

  // ---- epilogue
  const int fq = lane >> 4;
#pragma unroll
  for (int m = 0; m < 8; ++m) {
    const int row0 = bm + wr * 128 + m * 16 + fq * 4;
#pragma unroll
    for (int n = 0; n < 4; ++n) {
      const int col = bn + wc * 64 + n * 16 + fr;
#pragma unroll
      for (int r = 0; r < 4; ++r) {
        float v = acc[m][n][r];
        if constexpr (EPI == 1) {
          v = fmaxf(v + bias[col], 0.0f);
          Cb[(size_t)(row0 + r) * ldc + col] = f2bf(v);
        } else {
          Cb[(size_t)(row0 + r) * ldc + col] = f2bf(v);
        }
      }
    }
  }
}

// ---------------- GEMM 256x128 (separate kernel; round-6 schedule, NFR=1) ----------
// Validated in round 10 as gemm256<*,128>. EPI 2: bf16 (ldc). EPI 4: f32 partial,
// blockIdx.z K-split. vmcnt(3): 6 loads/tile, wait leaves kt+2's 3.
template <int EPI>
__global__ __launch_bounds__(512, 1) void gemm_bn128(
    const unsigned short* __restrict__ A, const unsigned short* __restrict__ Bt,
    unsigned short* __restrict__ Cb, float* __restrict__ Cf,
    int M, int N, int K, int lda, int ldb, int ldc, size_t pstride) {
  __shared__ __align__(16) unsigned short ldsA[2][256 * 64];
  __shared__ __align__(16) unsigned short ldsB[2][128 * 64];

  const size_t koff = (size_t)blockIdx.z * K;
  A += koff; Bt += koff;
  Cf += (size_t)blockIdx.z * pstride;

  const int tid = threadIdx.x;
  const int wid = tid >> 6;
  const int lane = tid & 63;
  const int wr = wid >> 2;      // 0..1  (128-row band)
  const int wc = wid & 3;       // 0..3  (32-col band)
  const int fr = lane & 15;
  const int kq = lane >> 4;

  const int nx = gridDim.x;
  const int nwg = nx * gridDim.y;
  const int bid = blockIdx.y * nx + blockIdx.x;
  const int q = nwg >> 3, r8 = nwg & 7;
  const int xcd = bid & 7, idx = bid >> 3;
  const int wg = (xcd < r8 ? xcd * (q + 1) : r8 * (q + 1) + (xcd - r8) * q) + idx;
  const int bn = (wg % nx) * 128;
  const int bm = (wg / nx) * 256;

  const int NT = K >> 6;

  const int st_r = tid >> 3;
  const int st_x = (tid & 7) << 4;
  const int colb = st_x ^ ((st_r & 7) << 4);
  const unsigned short* gbA[2][2];
  const unsigned short* gbB[2];
#pragma unroll
  for (int half = 0; half < 2; ++half) {
#pragma unroll
    for (int iss = 0; iss < 2; ++iss) {
      const int row = half * 128 + iss * 64 + st_r;
      gbA[half][iss] = A + (size_t)(bm + row) * lda + (colb >> 1);
    }
    gbB[half] = Bt + (size_t)(bn + half * 64 + st_r) * ldb + (colb >> 1);
  }
  const int widb = wid << 10;

  auto stageA = [&](auto dbufc, int half, int kt) {
    constexpr int dbuf = decltype(dbufc)::value;
#pragma unroll
    for (int iss = 0; iss < 2; ++iss) {
      const unsigned short* g = gbA[half][iss] + ((size_t)kt << 6);
      char* l = (char*)&ldsA[dbuf][0] + (half * 2 + iss) * 8192 + widb;
      gload16(g, l);
    }
  };
  auto stageB = [&](auto dbufc, int half, int kt) {
    constexpr int dbuf = decltype(dbufc)::value;
    const unsigned short* g = gbB[half] + ((size_t)kt << 6);
    char* l = (char*)&ldsB[dbuf][0] + half * 8192 + widb;
    gload16(g, l);
  };

  const int swz = (fr & 7) << 4;
  const int arow = (wr * 128 + fr) * 128;
  const int brow = (wc * 32 + fr) * 128;
  const int col0 = (kq * 16) ^ swz;
  const int col1 = (64 + kq * 16) ^ swz;
  auto rdA = [&](auto bufc, int mh, int m, int kk) -> bf16x8 {
    constexpr int buf = decltype(bufc)::value;
    const int off = arow + mh * 8192 + m * 2048 + (kk ? col1 : col0);
    return *(const bf16x8*)((const char*)&ldsA[buf][0] + off);
  };
  auto rdB = [&](auto bufc, int nh, int kk) -> bf16x8 {
    constexpr int buf = decltype(bufc)::value;
    const int off = brow + nh * 2048 + (kk ? col1 : col0);
    return *(const bf16x8*)((const char*)&ldsB[buf][0] + off);
  };

  f32x4 acc[8][2] = {};
  bf16x8 a[4][2], b0[2], b1[2];

  stageB(IC<0>{}, 0, 0);
  stageA(IC<0>{}, 0, 0);
  stageB(IC<0>{}, 1, 0);
  stageA(IC<0>{}, 1, 0);
  if (NT > 1) {
    stageB(IC<1>{}, 0, 1);
    stageA(IC<1>{}, 0, 1);
    asm volatile("s_waitcnt vmcnt(3)" ::: "memory");
  } else {
    asm volatile("s_waitcnt vmcnt(0)" ::: "memory");
  }
  __builtin_amdgcn_sched_barrier(0);
  __builtin_amdgcn_s_barrier();
  __builtin_amdgcn_sched_barrier(0);

  auto ktile = [&](auto bufc, int kt) {
    constexpr int buf = decltype(bufc)::value;
    constexpr int nbuf = buf ^ 1;
    IC<buf> B_; IC<nbuf> NB_;

    // ph0
#pragma unroll
    for (int m = 0; m < 4; ++m) {
      a[m][0] = rdA(B_, 0, m, 0);
      a[m][1] = rdA(B_, 0, m, 1);
    }
    b0[0] = rdB(B_, 0, 0);
    b0[1] = rdB(B_, 0, 1);
    if (kt + 1 < NT) stageB(NB_, 1, kt + 1);
    __builtin_amdgcn_s_barrier();
    __builtin_amdgcn_s_setprio(1);
#pragma unroll
    for (int m = 0; m < 4; ++m)
#pragma unroll
      for (int kk = 0; kk < 2; ++kk)
        acc[m][0] = __builtin_amdgcn_mfma_f32_16x16x32_bf16(a[m][kk], b0[kk], acc[m][0], 0, 0, 0);
    __builtin_amdgcn_s_setprio(0);
    __builtin_amdgcn_s_barrier();
    __builtin_amdgcn_sched_barrier(0);

    // ph1
    b1[0] = rdB(B_, 1, 0);
    b1[1] = rdB(B_, 1, 1);
    if (kt + 1 < NT) stageA(NB_, 1, kt + 1);
    __builtin_amdgcn_s_barrier();
    __builtin_amdgcn_s_setprio(1);
#pragma unroll
    for (int m = 0; m < 4; ++m)
#pragma unroll
      for (int kk = 0; kk < 2; ++kk)
        acc[m][1] = __builtin_amdgcn_mfma_f32_16x16x32_bf16(a[m][kk], b1[kk], acc[m][1], 0, 0, 0);
    __builtin_amdgcn_s_setprio(0);
    __builtin_amdgcn_s_barrier();
    __builtin_amdgcn_sched_barrier(0);

    // ph2
#pragma unroll
    for (int m = 0; m < 4; ++m) {
      a[m][0] = rdA(B_, 1, m, 0);
      a[m][1] = rdA(B_, 1, m, 1);
    }
    if (kt + 2 < NT) stageB(B_, 0, kt + 2);
    __builtin_amdgcn_s_barrier();
    __builtin_amdgcn_s_setprio(1);
#pragma unroll
    for (int m = 0; m < 4; ++m)
#pragma unroll
      for (int kk = 0; kk < 2; ++kk)
        acc[m + 4][1] = __builtin_amdgcn_mfma_f32_16x16x32_bf16(a[m][kk], b1[kk], acc[m + 4][1], 0, 0, 0);
    __builtin_amdgcn_s_setprio(0);
    __builtin_amdgcn_s_barrier();
    __builtin_amdgcn_sched_barrier(0);

    // ph3
    if (kt + 2 < NT) {
      stageA(B_, 0, kt + 2);
      asm volatile("s_waitcnt vmcnt(3)" ::: "memory");
    } else {
      asm volatile("s_waitcnt vmcnt(0)" ::: "memory");
    }
    __builtin_amdgcn_sched_barrier(0);
    __builtin_amdgcn_s_barrier();
    __builtin_amdgcn_s_setprio(1);
#pragma unroll
    for (int m = 0; m < 4; ++m)
#pragma unroll
      for (int kk = 0; kk < 2; ++kk)
        acc[m + 4][0] = __builtin_amdgcn_mfma_f32_16x16x32_bf16(a[m][kk], b0[kk], acc[m + 4][0], 0, 0, 0);
    __builtin_amdgcn_s_setprio(0);
    __builtin_amdgcn_s_barrier();
    __builtin_amdgcn_sched_barrier(0);
  };

  for (int kt = 0; kt < NT; kt += 2) {
    ktile(IC<0>{}, kt);
    ktile(IC<1>{}, kt + 1);
  }

  const int fq = lane >> 4;
#pragma unroll
  for (int m = 0; m < 8; ++m) {
    const int row0 = bm + wr * 128 + m * 16 + fq * 4;
#pragma unroll
    for (int nh = 0; nh < 2; ++nh) {
      const int col = bn + wc * 32 + nh * 16 + fr;
#pragma unroll
      for (int r = 0; r < 4; ++r) {
        float v = acc[m][nh][r];
        if constexpr (EPI == 2) {
          Cb[(size_t)(row0 + r) * ldc + col] = f2bf(v);
        } else {
          Cf[(size_t)(row0 + r) * ldc + col] = v;
        }
      }
    }
  }
}

// ---------------- launch ----------------
extern "C" void kernel_launch(void* const* d_in, const int* in_sizes, int n_in,
                              void* d_out, int out_size, void* d_ws, size_t ws_size,
                              hipStream_t stream) {
  const float* enc  = (const float*)d_in[0];
  const float* mem  = (const float*)d_in[1];
  const float* fw1  = (const float*)d_in[2];
  const float* fb1  = (const float*)d_in[3];
  const float* fw2  = (const float*)d_in[4];
  const float* fb2  = (const float*)d_in[5];
  float* out = (float*)d_out;

  const int B = 4096, M = 8192, D = 2048, HID = 8192, OUT = 1000, OUTP = 1024;

  char* p = (char*)d_ws;
  auto alloc = [&](size_t bytes) {
    char* r = p;
    p += (bytes + 255) & ~(size_t)255;
    return r;
  };
  unsigned short* memB = (unsigned short*)alloc((size_t)M * D * 2);        // 32 MB
  unsigned short* memT = (unsigned short*)alloc((size_t)D * M * 2);        // 32 MB
  unsigned short* w1   = (unsigned short*)alloc((size_t)HID * 2 * D * 2);  // 64 MB
  unsigned short* w2   = (unsigned short*)alloc((size_t)OUTP * HID * 2);   // 16 MB
  unsigned short* wts  = (unsigned short*)alloc((size_t)B * M * 2);        // 64 MB
  unsigned short* fin  = (unsigned short*)alloc((size_t)B * 2 * D * 2);    // 32 MB
  float* rs            = (float*)alloc((size_t)B * 4);
  float* cs            = (float*)alloc((size_t)M * 4);
  float* pp            = (float*)alloc((size_t)2 * B * OUTP * 4);          // 32 MB partials
  unsigned short* hid  = (unsigned short*)alloc((size_t)B * HID * 2);      // 64 MB
  unsigned short* simb = hid;  // alias: simb dead before fc1 writes hid

  // prep: norms + casts + weight converts in ONE launch
  prep_all<<<B + M + 2048, 256, 0, stream>>>(enc, mem, fw1, fw2, fin, memB, w1, w2,
                                             rs, cs, B, M, D, 2 * D,
                                             (long)HID * 2 * D / 4, (long)OUT * HID / 4);
  transpose_bb<<<dim3(D / 64, M / 64), 256, 0, stream>>>(memB, memT, M, D);

  // raw sims = bf16(enc) @ bf16(mem)^T  [B, M] -> bf16 (norms folded into sparsemax)
  gemm256<2><<<dim3(M / 256, B / 256), 512, 0, stream>>>(fin, memB, nullptr, simb,
                                                         B, M, D, 2 * D, M);
  // sparsemax(z * rs * cs) -> dense bf16 weights
  sparsemax_scaled<<<B, 256, 0, stream>>>(simb, rs, cs, wts, M);
  // fin[:, D:2D) = wts @ mem  (256x128 tile: 16x16 = 256 blocks = 1/CU)
  gemm_bn128<2><<<dim3(D / 128, B / 256), 512, 0, stream>>>(
      wts, memT, fin + D, nullptr, B, D, M, M, M, 2 * D, 0);
  // hidden = relu(fin @ fc1_w^T + b1) -> bf16
  gemm256<1><<<dim3(HID / 256, B / 256), 512, 0, stream>>>(fin, w1, fb1, hid,
                                                           B, HID, 2 * D, 2 * D, HID);
  // out partials: hidden @ fc2_w^T, split-K=2 via grid.z (8x16x2 = 256 blocks)
  gemm_bn128<4><<<dim3(OUTP / 128, B / 256, 2), 512, 0, stream>>>(
      hid, w2, nullptr, pp, B, OUTP, HID / 2, HID, HID, OUTP, (size_t)B * OUTP);
  fc2_reduce<<<B, 256, 0, stream>>>(pp, pp + (size_t)B * OUTP, fb2, out);
}